// Round 8
// baseline (974.223 us; speedup 1.0000x reference)
//
#include <hip/hip_runtime.h>
#include <hip/hip_bf16.h>

#define N_NODESC 100000
#define N_EDGESC 200000
#define BG 2048
#define NDIM 64
#define EDIM 16
#define G2CH 25000

typedef __bf16 bf16x8 __attribute__((ext_vector_type(8)));
typedef float f32x4 __attribute__((ext_vector_type(4)));

static __device__ __forceinline__ float bn_inv() { return 0.9999950000374997f; }

static __device__ __forceinline__ float b2f(short s) {
    __hip_bfloat16 h = *(const __hip_bfloat16*)&s;
    return __bfloat162float(h);
}

// async global->LDS 16B per lane; LDS dest = wave-uniform base + lane*16
__device__ __forceinline__ void gl2lds16(const void* g, void* l) {
    __builtin_amdgcn_global_load_lds(
        (const __attribute__((address_space(1))) unsigned int*)g,
        (__attribute__((address_space(3))) unsigned int*)l, 16, 0, 0);
}

// ---------------- zero fills --------------------------------------------------
__global__ void zero_f4(float4* __restrict__ p, int n4) {
    int i = blockIdx.x * 256 + threadIdx.x;
    if (i < n4) p[i] = make_float4(0.f, 0.f, 0.f, 0.f);
}
__global__ void zero_int(int* __restrict__ p, int n) {
    int i = blockIdx.x * 256 + threadIdx.x;
    if (i < n) p[i] = 0;
}
__global__ void zero_out(float* __restrict__ p, int n) {
    int i = blockIdx.x * 256 + threadIdx.x;
    if (i < n) p[i] = 0.f;
}

// ---------------- CSR build: histogram -> scan -> scatter --------------------
__global__ void hist_dst(const int* __restrict__ dst, int* __restrict__ deg) {
    int i = blockIdx.x * 256 + threadIdx.x;
    if (i < N_EDGESC) atomicAdd(&deg[dst[i]], 1);
}
__global__ void scan_bsums(const int* __restrict__ deg, int* __restrict__ bsum, int n) {
    __shared__ int ls[256];
    int b = blockIdx.x, t = threadIdx.x;
    int s = 0;
#pragma unroll
    for (int j = 0; j < 4; j++) {
        int i = b * 1024 + t * 4 + j;
        if (i < n) s += deg[i];
    }
    ls[t] = s;
    __syncthreads();
    for (int off = 128; off; off >>= 1) {
        if (t < off) ls[t] += ls[t + off];
        __syncthreads();
    }
    if (t == 0) bsum[b] = ls[0];
}
__global__ void scan_top(int* __restrict__ bsum, int nb, int* __restrict__ total) {
    if (threadIdx.x == 0) {
        int acc = 0;
        for (int i = 0; i < nb; i++) { int v = bsum[i]; bsum[i] = acc; acc += v; }
        *total = acc;
    }
}
__global__ void scan_final(const int* __restrict__ deg, const int* __restrict__ bsum,
                           int* __restrict__ rowptr, int* __restrict__ cursor, int n) {
    __shared__ int ls[256];
    int b = blockIdx.x, t = threadIdx.x;
    int v[4], s = 0;
#pragma unroll
    for (int j = 0; j < 4; j++) {
        int i = b * 1024 + t * 4 + j;
        v[j] = (i < n) ? deg[i] : 0;
        s += v[j];
    }
    ls[t] = s;
    __syncthreads();
    int run = s;
    for (int off = 1; off < 256; off <<= 1) {
        int add = (t >= off) ? ls[t - off] : 0;
        __syncthreads();
        ls[t] += add;
        __syncthreads();
    }
    int excl = ls[t] - run + bsum[b];
#pragma unroll
    for (int j = 0; j < 4; j++) {
        int i = b * 1024 + t * 4 + j;
        if (i < n) { rowptr[i] = excl; cursor[i] = excl; excl += v[j]; }
    }
}
__global__ void scatter_eid(const int* __restrict__ dst, int* __restrict__ cursor,
                            int* __restrict__ eid) {
    int e = blockIdx.x * 256 + threadIdx.x;
    if (e < N_EDGESC) {
        int p = atomicAdd(&cursor[dst[e]], 1);
        eid[p] = e;
    }
}

// ---------------- W [K][N] f32 -> bf16 [N][K] --------------------------------
__global__ void transpose_w(const float* __restrict__ W, __hip_bfloat16* __restrict__ hi,
                            int K, int N) {
    __shared__ float t[64][65];
    int k0 = blockIdx.x * 64, n0 = blockIdx.y * 64;
    int tid = threadIdx.x, tx = tid & 63, ty = tid >> 6;
    for (int r = ty; r < 64; r += 4) t[r][tx] = W[(size_t)(k0 + r) * N + n0 + tx];
    __syncthreads();
    for (int r = ty; r < 64; r += 4)
        hi[(size_t)(n0 + r) * K + k0 + tx] = __float2bfloat16(t[tx][r]);
}

__global__ void concat_bias(const float* __restrict__ a, const float* __restrict__ b,
                            float* __restrict__ o) {
    int i = blockIdx.x * 256 + threadIdx.x;
    if (i < 2048) { o[i] = a[i]; o[2048 + i] = b[i]; }
}

// ---------------- GINE1 gather -----------------------------------------------
#define G1_NPW 8
__global__ __launch_bounds__(256, 2) void gine1_gather(
    const float* __restrict__ x, const int* __restrict__ srcv, const float* __restrict__ ea,
    const float* __restrict__ e1W, const float* __restrict__ e1b,
    const int* __restrict__ rowptr, const int* __restrict__ eid,
    __hip_bfloat16* __restrict__ xin) {
    int tid = threadIdx.x;
    int wave = tid >> 6, lane = tid & 63;
    float wreg[16];
#pragma unroll
    for (int k = 0; k < 16; k++) wreg[k] = e1W[k * 64 + lane];
    float bb = e1b[lane];
    int nbase = (blockIdx.x * 4 + wave) * G1_NPW;
#pragma unroll 1
    for (int it = 0; it < G1_NPW; it++) {
        int n = nbase + it;
        if (n >= N_NODESC) return;
        float acc = x[(size_t)n * 64 + lane];
        int beg = rowptr[n], end = rowptr[n + 1];
        for (int idx = beg; idx < end; idx++) {
            int e = eid[idx], s = srcv[e];
            const float4* ef = (const float4*)(ea + (size_t)e * 16);
            float4 e0 = ef[0], e1 = ef[1], e2 = ef[2], e3 = ef[3];
            float p = bb;
            p = fmaf(e0.x, wreg[0], p);  p = fmaf(e0.y, wreg[1], p);
            p = fmaf(e0.z, wreg[2], p);  p = fmaf(e0.w, wreg[3], p);
            p = fmaf(e1.x, wreg[4], p);  p = fmaf(e1.y, wreg[5], p);
            p = fmaf(e1.z, wreg[6], p);  p = fmaf(e1.w, wreg[7], p);
            p = fmaf(e2.x, wreg[8], p);  p = fmaf(e2.y, wreg[9], p);
            p = fmaf(e2.z, wreg[10], p); p = fmaf(e2.w, wreg[11], p);
            p = fmaf(e3.x, wreg[12], p); p = fmaf(e3.y, wreg[13], p);
            p = fmaf(e3.z, wreg[14], p); p = fmaf(e3.w, wreg[15], p);
            acc += fmaxf(x[(size_t)s * 64 + lane] + p, 0.f);
        }
        xin[(size_t)n * 64 + lane] = __float2bfloat16(acc);
    }
}

// ---------------- GINE2 gather body ------------------------------------------
// Round-3 structure (confirmed win): 2 cols/thread, 2-edge-unrolled inner loop.
// Body parameterized by virtual block id so it can run standalone or fused.
#define G2_NPB 8
static __device__ void gather2_body(
    int gbid, const __hip_bfloat16* __restrict__ h, const int* __restrict__ srcv,
    const float* __restrict__ ea, const float* __restrict__ e2W,
    const float* __restrict__ e2b, const int* __restrict__ rowptr,
    const int* __restrict__ eid, __hip_bfloat16* __restrict__ a2, int n0, int n1) {
    int tid = threadIdx.x;
    int c0 = tid * 2;
    float wreg[2][16], breg[2];
#pragma unroll
    for (int j = 0; j < 2; j++) {
        breg[j] = e2b[c0 + j];
#pragma unroll
        for (int k = 0; k < 16; k++) wreg[j][k] = e2W[k * 512 + c0 + j];
    }
    int nbase = n0 + gbid * G2_NPB;
#pragma unroll 1
    for (int it = 0; it < G2_NPB; it++) {
        int n = nbase + it;
        if (n >= n1) return;
        unsigned int hv = *(const unsigned int*)((const short*)(h + (size_t)n * 512) + c0);
        const __hip_bfloat16* hb = (const __hip_bfloat16*)&hv;
        float acc[2] = {__bfloat162float(hb[0]), __bfloat162float(hb[1])};
        int beg = rowptr[n], end = rowptr[n + 1];
        int idx = beg;
#pragma unroll 1
        for (; idx + 2 <= end; idx += 2) {
            int ei0 = eid[idx], ei1 = eid[idx + 1];
            int s0 = srcv[ei0], s1 = srcv[ei1];
            const float4* ef0 = (const float4*)(ea + (size_t)ei0 * 16);
            const float4* ef1 = (const float4*)(ea + (size_t)ei1 * 16);
            float4 a0 = ef0[0], a1 = ef0[1], a2v = ef0[2], a3 = ef0[3];
            float4 b0 = ef1[0], b1 = ef1[1], b2v = ef1[2], b3 = ef1[3];
            unsigned int sv0 = *(const unsigned int*)((const short*)(h + (size_t)s0 * 512) + c0);
            unsigned int sv1 = *(const unsigned int*)((const short*)(h + (size_t)s1 * 512) + c0);
            const __hip_bfloat16* sb0 = (const __hip_bfloat16*)&sv0;
            const __hip_bfloat16* sb1 = (const __hip_bfloat16*)&sv1;
#pragma unroll
            for (int j = 0; j < 2; j++) {
                float p = breg[j];
                p = fmaf(a0.x, wreg[j][0], p);  p = fmaf(a0.y, wreg[j][1], p);
                p = fmaf(a0.z, wreg[j][2], p);  p = fmaf(a0.w, wreg[j][3], p);
                p = fmaf(a1.x, wreg[j][4], p);  p = fmaf(a1.y, wreg[j][5], p);
                p = fmaf(a1.z, wreg[j][6], p);  p = fmaf(a1.w, wreg[j][7], p);
                p = fmaf(a2v.x, wreg[j][8], p); p = fmaf(a2v.y, wreg[j][9], p);
                p = fmaf(a2v.z, wreg[j][10], p);p = fmaf(a2v.w, wreg[j][11], p);
                p = fmaf(a3.x, wreg[j][12], p); p = fmaf(a3.y, wreg[j][13], p);
                p = fmaf(a3.z, wreg[j][14], p); p = fmaf(a3.w, wreg[j][15], p);
                acc[j] += fmaxf(__bfloat162float(sb0[j]) + p, 0.f);
                float q = breg[j];
                q = fmaf(b0.x, wreg[j][0], q);  q = fmaf(b0.y, wreg[j][1], q);
                q = fmaf(b0.z, wreg[j][2], q);  q = fmaf(b0.w, wreg[j][3], q);
                q = fmaf(b1.x, wreg[j][4], q);  q = fmaf(b1.y, wreg[j][5], q);
                q = fmaf(b1.z, wreg[j][6], q);  q = fmaf(b1.w, wreg[j][7], q);
                q = fmaf(b2v.x, wreg[j][8], q); q = fmaf(b2v.y, wreg[j][9], q);
                q = fmaf(b2v.z, wreg[j][10], q);q = fmaf(b2v.w, wreg[j][11], q);
                q = fmaf(b3.x, wreg[j][12], q); q = fmaf(b3.y, wreg[j][13], q);
                q = fmaf(b3.z, wreg[j][14], q); q = fmaf(b3.w, wreg[j][15], q);
                acc[j] += fmaxf(__bfloat162float(sb1[j]) + q, 0.f);
            }
        }
        if (idx < end) {
            int ei = eid[idx];
            int s = srcv[ei];
            const float4* ef = (const float4*)(ea + (size_t)ei * 16);
            float4 a0 = ef[0], a1 = ef[1], a2v = ef[2], a3 = ef[3];
            unsigned int sv = *(const unsigned int*)((const short*)(h + (size_t)s * 512) + c0);
            const __hip_bfloat16* sb = (const __hip_bfloat16*)&sv;
#pragma unroll
            for (int j = 0; j < 2; j++) {
                float p = breg[j];
                p = fmaf(a0.x, wreg[j][0], p);  p = fmaf(a0.y, wreg[j][1], p);
                p = fmaf(a0.z, wreg[j][2], p);  p = fmaf(a0.w, wreg[j][3], p);
                p = fmaf(a1.x, wreg[j][4], p);  p = fmaf(a1.y, wreg[j][5], p);
                p = fmaf(a1.z, wreg[j][6], p);  p = fmaf(a1.w, wreg[j][7], p);
                p = fmaf(a2v.x, wreg[j][8], p); p = fmaf(a2v.y, wreg[j][9], p);
                p = fmaf(a2v.z, wreg[j][10], p);p = fmaf(a2v.w, wreg[j][11], p);
                p = fmaf(a3.x, wreg[j][12], p); p = fmaf(a3.y, wreg[j][13], p);
                p = fmaf(a3.z, wreg[j][14], p); p = fmaf(a3.w, wreg[j][15], p);
                acc[j] += fmaxf(__bfloat162float(sb[j]) + p, 0.f);
            }
        }
        __hip_bfloat16 o[2];
        o[0] = __float2bfloat16(acc[0]);
        o[1] = __float2bfloat16(acc[1]);
        *(unsigned int*)((short*)(a2 + (size_t)(n - n0) * 512) + c0) = *(const unsigned int*)o;
    }
}

__global__ __launch_bounds__(256, 5) void gine2_gather(
    const __hip_bfloat16* __restrict__ h, const int* __restrict__ srcv,
    const float* __restrict__ ea, const float* __restrict__ e2W,
    const float* __restrict__ e2b, const int* __restrict__ rowptr,
    const int* __restrict__ eid, __hip_bfloat16* __restrict__ a2, int n0, int n1) {
    gather2_body(blockIdx.x, h, srcv, ea, e2W, e2b, rowptr, eid, a2, n0, n1);
}

// ---------------- MFMA GEMM body: C[M,N] = A[M,K] @ B^T[N,K] (bf16) ----------
// m97 schedule + T1 XCD swizzle + BK=64 + LDS-bounce epilogue (round-6) +
// MODE-2 quad-reduced atomics (round-5). Body parameterized by virtual block
// coords so it can run standalone or inside the fused GINE2 kernel.
template <int MODE>
static __device__ void gemm_body(
    int vbx, int vby, int nwgx, int nwgy,
    const __hip_bfloat16* __restrict__ A, const __hip_bfloat16* __restrict__ Bhi,
    int M, int K, int N, const float* __restrict__ bias, const float* __restrict__ bng,
    const float* __restrict__ bnb, const int* __restrict__ batch,
    float* __restrict__ psum, __hip_bfloat16* __restrict__ Cout, short* buf) {
    short* AsP = buf;           // As[h] = AsP + h*4096, [128][32] each
    short* BhP = buf + 8192;    // Bh[h] = BhP + h*4096

    int nwg = nwgx * nwgy;
    int wg = vbx + nwgx * vby;
    int q = nwg >> 3, r = nwg & 7;
    int xcd = wg & 7, idx = wg >> 3;
    int swz = (xcd < r) ? (xcd * (q + 1) + idx)
                        : (r * (q + 1) + (xcd - r) * q + idx);
    int bx = swz % nwgx, by = swz / nwgx;

    int r0 = by * 128;
    int n0 = bx * 128;
    int tid = threadIdx.x;
    int lane = tid & 63;
    int wv = tid >> 6;
    int wm = (wv >> 1) * 64, wn = (wv & 1) * 64;

    f32x4 acc[4][4];
#pragma unroll
    for (int i = 0; i < 4; i++)
#pragma unroll
        for (int j = 0; j < 4; j++) acc[i][j] = (f32x4){0.f, 0.f, 0.f, 0.f};

    // staging indices: linear i in [0,512), row = i>>2, kb = i&3; LDS offset = i*16B
    int rowA0 = tid >> 2, cbA0 = tid & 3;
    int rowA1 = (tid + 256) >> 2;  // (tid+256)&3 == tid&3
    int gA0 = r0 + rowA0; if (gA0 >= M) gA0 = M - 1;
    int gA1 = r0 + rowA1; if (gA1 >= M) gA1 = M - 1;
    const __hip_bfloat16* pA0 = A + (size_t)gA0 * K + cbA0 * 8;
    const __hip_bfloat16* pA1 = A + (size_t)gA1 * K + cbA0 * 8;
    const __hip_bfloat16* pB0 = Bhi + (size_t)(n0 + rowA0) * K + cbA0 * 8;
    const __hip_bfloat16* pB1 = Bhi + (size_t)(n0 + rowA1) * K + cbA0 * 8;

    int fi = lane & 15, kb = (lane >> 4) * 8;
    for (int k0 = 0; k0 < K; k0 += 64) {
        __syncthreads();
        // stage BOTH 32-wide halves before one drain (8 gl2lds16/thread)
#pragma unroll
        for (int hh = 0; hh < 2; hh++) {
            int kk = k0 + hh * 32;
            gl2lds16(pA0 + kk, AsP + hh * 4096 + wv * 512);
            gl2lds16(pA1 + kk, AsP + hh * 4096 + 2048 + wv * 512);
            gl2lds16(pB0 + kk, BhP + hh * 4096 + wv * 512);
            gl2lds16(pB1 + kk, BhP + hh * 4096 + 2048 + wv * 512);
        }
        __syncthreads();
#pragma unroll
        for (int ks = 0; ks < 2; ks++) {
            bf16x8 af[4], bhf[4];
#pragma unroll
            for (int mi = 0; mi < 4; mi++)
                af[mi] = *(const bf16x8*)(AsP + ks * 4096 + (wm + mi * 16 + fi) * 32 + kb);
#pragma unroll
            for (int ni = 0; ni < 4; ni++)
                bhf[ni] = *(const bf16x8*)(BhP + ks * 4096 + (wn + ni * 16 + fi) * 32 + kb);
#pragma unroll
            for (int mi = 0; mi < 4; mi++)
#pragma unroll
                for (int ni = 0; ni < 4; ni++)
                    acc[mi][ni] = __builtin_amdgcn_mfma_f32_16x16x32_bf16(
                        af[mi], bhf[ni], acc[mi][ni], 0, 0, 0);
        }
    }
    int col_l = lane & 15, quad = lane >> 4;
    if (MODE == 0 || MODE == 1) {
        // ---- LDS-bounce epilogue: fragments -> [128][132] tile -> wide stores
        __syncthreads();  // all K-loop ds_reads complete before overwriting buf
#pragma unroll
        for (int mi = 0; mi < 4; mi++) {
            int rloc = wm + mi * 16 + quad * 4;
#pragma unroll
            for (int ni = 0; ni < 4; ni++) {
                int cloc = wn + ni * 16 + col_l;
                float b0 = bias[n0 + cloc];
                float g0 = 0.f, bb0 = 0.f;
                if (MODE == 1) { g0 = bng[n0 + cloc]; bb0 = bnb[n0 + cloc]; }
#pragma unroll
                for (int reg = 0; reg < 4; reg++) {
                    float v = acc[mi][ni][reg] + b0;
                    if (MODE == 1) v = fmaxf(fmaf(v * bn_inv(), g0, bb0), 0.f);
                    __hip_bfloat16 hv = __float2bfloat16(v);
                    buf[(rloc + reg) * 132 + cloc] = *(const short*)&hv;
                }
            }
        }
        __syncthreads();
        // stream out: 8 rows per pass (32 lanes x 8B = 256B/row, full lines)
#pragma unroll
        for (int p = 0; p < 16; p++) {
            int row = p * 8 + (tid >> 5);
            int grow = r0 + row;
            if (grow < M) {
                int c4 = (tid & 31) * 4;
                short4 v = *(const short4*)(buf + row * 132 + c4);
                *(short4*)(Cout + (size_t)grow * N + n0 + c4) = v;
            }
        }
    } else {
#pragma unroll
        for (int mi = 0; mi < 4; mi++) {
            int rbase = r0 + wm + mi * 16 + quad * 4;
#pragma unroll
            for (int ni = 0; ni < 4; ni++) {
                int gcol = n0 + wn + ni * 16 + col_l;
                float b0 = bias[gcol], g0 = bng[gcol], bb0 = bnb[gcol];
                float vv[4];
#pragma unroll
                for (int reg = 0; reg < 4; reg++)
                    vv[reg] = fmaxf(fmaf((acc[mi][ni][reg] + b0) * bn_inv(), g0, bb0), 0.f);
                // rows covered by this wave's mi: rtop .. rtop+15 (wave-uniform)
                int rtop = r0 + wm + mi * 16;
                bool uni16 = (rtop + 15 < M) && (batch[rtop] == batch[rtop + 15]);
                float vs = (vv[0] + vv[1]) + (vv[2] + vv[3]);
                if (uni16) {
                    // sum the 4 quads' 4-row partials: lanes ^16, ^32 keep col_l
                    vs += __shfl_xor(vs, 16);
                    vs += __shfl_xor(vs, 32);
                    if (quad == 0)
                        atomicAdd(&psum[(size_t)batch[rtop] * 512 + gcol], vs);
                } else if (rbase + 3 < M && batch[rbase] == batch[rbase + 3]) {
                    atomicAdd(&psum[(size_t)batch[rbase] * 512 + gcol], vs);
                } else {
#pragma unroll
                    for (int reg = 0; reg < 4; reg++) {
                        int grow = rbase + reg;
                        if (grow < M)
                            atomicAdd(&psum[(size_t)batch[grow] * 512 + gcol], vv[reg]);
                    }
                }
            }
        }
    }
}

template <int MODE>
__global__ __launch_bounds__(256, 4) void mfma_gemm(
    const __hip_bfloat16* __restrict__ A, const __hip_bfloat16* __restrict__ Bhi,
    int M, int K, int N, const float* __restrict__ bias, const float* __restrict__ bng,
    const float* __restrict__ bnb, const int* __restrict__ batch,
    float* __restrict__ psum, __hip_bfloat16* __restrict__ Cout) {
    __shared__ __align__(16) short buf[16896];
    gemm_body<MODE>(blockIdx.x, blockIdx.y, gridDim.x, gridDim.y, A, Bhi, M, K, N,
                    bias, bng, bnb, batch, psum, Cout, buf);
}

// ---------------- fused GINE2: gemm(chunk c) || gather(chunk c+1) ------------
// Round-8: the two are data-independent; the gather is latency-bound (VALU ~29%,
// occ 31%) and the gemm is stall-bound (MFMA ~14%, all pipes idle). Co-residency
// on each CU fills each other's stalls (m114 mechanism: MFMA and VALU pipes
// overlap fully across waves). Role split: every 5th block is a gemm block
// (784 gemm vs 3125 gather blocks per 25k chunk).
__global__ __launch_bounds__(256, 4) void gine2_fused(
    const __hip_bfloat16* __restrict__ h, const int* __restrict__ srcv,
    const float* __restrict__ ea, const float* __restrict__ e2W,
    const float* __restrict__ e2b, const int* __restrict__ rowptr,
    const int* __restrict__ eid,
    const __hip_bfloat16* __restrict__ A2r, __hip_bfloat16* __restrict__ A2w,
    const __hip_bfloat16* __restrict__ G2Wp, const float* __restrict__ g2b,
    const float* __restrict__ bng, const float* __restrict__ bnb,
    const int* __restrict__ batchc, float* __restrict__ psum,
    int gemmM, int gemmNwgy, int gn0, int gn1, int ngb) {
    __shared__ __align__(16) short buf[16896];
    int bid = blockIdx.x;
    int q = bid / 5, r = bid % 5;
    if (r == 2) {
        gemm_body<2>(q & 3, q >> 2, 4, gemmNwgy, A2r, G2Wp, gemmM, 512, 512,
                     g2b, bng, bnb, batchc, psum, nullptr, buf);
    } else {
        int gid = q * 4 + (r < 2 ? r : r - 1);
        if (gid < ngb)
            gather2_body(gid, h, srcv, ea, e2W, e2b, rowptr, eid, A2w, gn0, gn1);
    }
}

// ---------------- node counts per graph --------------------------------------
__global__ void count_nodes(const int* __restrict__ batch, float* __restrict__ cnt) {
    int i = blockIdx.x * 256 + threadIdx.x;
    if (i < N_NODESC) atomicAdd(&cnt[batch[i]], 1.0f);
}

// ---------------- finalize pool + assemble xn [B,7,512] bf16 -----------------
__global__ void build_xn(const float* __restrict__ psum, const float* __restrict__ cnt,
                         const float* __restrict__ ecfp, const float* __restrict__ topo,
                         const float* __restrict__ maccs, const float* __restrict__ estate,
                         const float* __restrict__ rdkit2d, const float* __restrict__ phar2d,
                         __hip_bfloat16* __restrict__ xn) {
    int i = blockIdx.x * 256 + threadIdx.x;
    if (i >= BG * 512) return;
    int bidx = i >> 9, c = i & 511;
    float cv = fmaxf(cnt[bidx], 1.0f);
    __hip_bfloat16* o = xn + (size_t)bidx * 7 * 512;
    o[c] = __float2bfloat16(psum[i] / cv);
    o[512 + c] = __float2bfloat16(ecfp[i]);
    o[2 * 512 + c] = __float2bfloat16(topo[i]);
    o[3 * 512 + c] = __float2bfloat16(maccs[i]);
    o[4 * 512 + c] = __float2bfloat16(estate[i]);
    o[5 * 512 + c] = __float2bfloat16(rdkit2d[i]);
    o[6 * 512 + c] = __float2bfloat16(phar2d[i]);
}

// ---------------- GAT attention (fused gl|gr layout: C[B*7][4096]) -----------
// Round-7: vectorized (G13) -- short4 loads in both phases.
__global__ void gat_attn(const __hip_bfloat16* __restrict__ cg,
                         const float* __restrict__ att, const float* __restrict__ bias,
                         const float* __restrict__ bng, const float* __restrict__ bnb,
                         __hip_bfloat16* __restrict__ zout) {
    int b = blockIdx.x;
    int tid = threadIdx.x;
    int wave = tid >> 6, lane = tid & 63;
    __shared__ float logits[13][4];
    __shared__ float alpha[13][4];
    const size_t base = (size_t)b * 7 * 4096;
    for (int p = wave; p < 52; p += 4) {
        int e = p >> 2, hh = p & 3;
        int se = (e < 7) ? 0 : (e - 6);
        int de = (e < 6) ? (e + 1) : ((e == 6) ? 0 : (e - 6));
        const short* glp = (const short*)(cg + base + (size_t)se * 4096 + hh * 512) + lane * 8;
        const short* grp = (const short*)(cg + base + (size_t)de * 4096 + 2048 + hh * 512) + lane * 8;
        short4 gl0 = ((const short4*)glp)[0], gl1 = ((const short4*)glp)[1];
        short4 gr0 = ((const short4*)grp)[0], gr1 = ((const short4*)grp)[1];
        const float4* ap = (const float4*)(att + hh * 512 + lane * 8);
        float4 a0 = ap[0], a1 = ap[1];
        float s = 0.f, v;
        v = b2f(gl0.x) + b2f(gr0.x); v = (v >= 0.f) ? v : 0.2f * v; s = fmaf(v, a0.x, s);
        v = b2f(gl0.y) + b2f(gr0.y); v = (v >= 0.f) ? v : 0.2f * v; s = fmaf(v, a0.y, s);
        v = b2f(gl0.z) + b2f(gr0.z); v = (v >= 0.f) ? v : 0.2f * v; s = fmaf(v, a0.z, s);
        v = b2f(gl0.w) + b2f(gr0.w); v = (v >= 0.f) ? v : 0.2f * v; s = fmaf(v, a0.w, s);
        v = b2f(gl1.x) + b2f(gr1.x); v = (v >= 0.f) ? v : 0.2f * v; s = fmaf(v, a1.x, s);
        v = b2f(gl1.y) + b2f(gr1.y); v = (v >= 0.f) ? v : 0.2f * v; s = fmaf(v, a1.y, s);
        v = b2f(gl1.z) + b2f(gr1.z); v = (v >= 0.f) ? v : 0.2f * v; s = fmaf(v, a1.z, s);
        v = b2f(gl1.w) + b2f(gr1.w); v = (v >= 0.f) ? v : 0.2f * v; s = fmaf(v, a1.w, s);
#pragma unroll
        for (int off = 32; off; off >>= 1) s += __shfl_down(s, off);
        if (lane == 0) logits[e][hh] = s;
    }
    __syncthreads();
    if (tid < 24) {
        int n = 1 + (tid >> 2), hh = tid & 3;
        float la = logits[n - 1][hh], lb = logits[6 + n][hh];
        float m = fmaxf(la, lb);
        float ea = __expf(la - m), eb = __expf(lb - m);
        float inv = 1.f / (ea + eb);
        alpha[n - 1][hh] = ea * inv;
        alpha[6 + n][hh] = eb * inv;
    } else if (tid < 28) {
        alpha[6][tid & 3] = 1.f;
    }
    __syncthreads();
    // Phase 2: 7*128 units of 4 columns each
    for (int u = tid; u < 7 * 128; u += 256) {
        int n = u >> 7, c4 = (u & 127) * 4;
        float v0 = 0.f, v1 = 0.f, v2 = 0.f, v3 = 0.f;
        const short* g0 = (const short*)(cg + base) + c4;
        if (n == 0) {
#pragma unroll
            for (int hh = 0; hh < 4; hh++) {
                short4 t = *(const short4*)(g0 + hh * 512);
                float a = alpha[6][hh];
                v0 = fmaf(a, b2f(t.x), v0); v1 = fmaf(a, b2f(t.y), v1);
                v2 = fmaf(a, b2f(t.z), v2); v3 = fmaf(a, b2f(t.w), v3);
            }
        } else {
            const short* gn = (const short*)(cg + base + (size_t)n * 4096) + c4;
#pragma unroll
            for (int hh = 0; hh < 4; hh++) {
                short4 t = *(const short4*)(g0 + hh * 512);
                float a = alpha[n - 1][hh];
                v0 = fmaf(a, b2f(t.x), v0); v1 = fmaf(a, b2f(t.y), v1);
                v2 = fmaf(a, b2f(t.z), v2); v3 = fmaf(a, b2f(t.w), v3);
                short4 t2 = *(const short4*)(gn + hh * 512);
                float a2 = alpha[6 + n][hh];
                v0 = fmaf(a2, b2f(t2.x), v0); v1 = fmaf(a2, b2f(t2.y), v1);
                v2 = fmaf(a2, b2f(t2.z), v2); v3 = fmaf(a2, b2f(t2.w), v3);
            }
        }
        float4 bi = *(const float4*)(bias + c4);
        float4 gg = *(const float4*)(bng + c4);
        float4 bb = *(const float4*)(bnb + c4);
        v0 = fmaxf(fmaf(fmaf(v0, 0.25f, bi.x) * bn_inv(), gg.x, bb.x), 0.f);
        v1 = fmaxf(fmaf(fmaf(v1, 0.25f, bi.y) * bn_inv(), gg.y, bb.y), 0.f);
        v2 = fmaxf(fmaf(fmaf(v2, 0.25f, bi.z) * bn_inv(), gg.z, bb.z), 0.f);
        v3 = fmaxf(fmaf(fmaf(v3, 0.25f, bi.w) * bn_inv(), gg.w, bb.w), 0.f);
        __hip_bfloat16 o[4];
        o[0] = __float2bfloat16(v0); o[1] = __float2bfloat16(v1);
        o[2] = __float2bfloat16(v2); o[3] = __float2bfloat16(v3);
        *(short4*)((short*)(zout + (size_t)b * 7 * 512) + n * 512 + c4) = *(const short4*)o;
    }
}

// ---------------- final fc ----------------------------------------------------
__global__ void final_fc(const __hip_bfloat16* __restrict__ z, const float* __restrict__ fcW,
                         const float* __restrict__ fcb, float* __restrict__ out) {
    int b = blockIdx.x * 4 + (threadIdx.x >> 6);
    int lane = threadIdx.x & 63;
    if (b >= BG) return;
    const __hip_bfloat16* row = z + (size_t)b * 7 * 512;
    float s = 0.f;
#pragma unroll
    for (int j = 0; j < 8; j++)
        s = fmaf(__bfloat162float(row[lane + j * 64]), fcW[lane + j * 64], s);
#pragma unroll
    for (int off = 32; off; off >>= 1) s += __shfl_down(s, off);
    if (lane == 0) out[b] = s + fcb[0];
}

extern "C" void kernel_launch(void* const* d_in, const int* in_sizes, int n_in,
                              void* d_out, int out_size, void* d_ws, size_t ws_size,
                              hipStream_t stream) {
    const float* x = (const float*)d_in[0];
    const int* eidx = (const int*)d_in[1];
    const float* eattr = (const float*)d_in[2];
    const int* batch = (const int*)d_in[3];
    const float* ecfp = (const float*)d_in[4];
    const float* topo = (const float*)d_in[5];
    const float* maccs = (const float*)d_in[6];
    const float* estate = (const float*)d_in[7];
    const float* rdkit2d = (const float*)d_in[8];
    const float* phar2d = (const float*)d_in[9];
    const float* g1_W = (const float*)d_in[10];
    const float* g1_b = (const float*)d_in[11];
    const float* e1_W = (const float*)d_in[12];
    const float* e1_b = (const float*)d_in[13];
    const float* bn1_g = (const float*)d_in[14];
    const float* bn1_b = (const float*)d_in[15];
    const float* g2_W = (const float*)d_in[16];
    const float* g2_b = (const float*)d_in[17];
    const float* e2_W = (const float*)d_in[18];
    const float* e2_b = (const float*)d_in[19];
    const float* bn2_g = (const float*)d_in[20];
    const float* bn2_b = (const float*)d_in[21];
    const float* gat1_Wl = (const float*)d_in[22];
    const float* gat1_bl = (const float*)d_in[23];
    const float* gat1_Wr = (const float*)d_in[24];
    const float* gat1_br = (const float*)d_in[25];
    const float* gat1_att = (const float*)d_in[26];
    const float* gat1_bias = (const float*)d_in[27];
    const float* bn3_g = (const float*)d_in[28];
    const float* bn3_b = (const float*)d_in[29];
    const float* gat2_Wl = (const float*)d_in[30];
    const float* gat2_bl = (const float*)d_in[31];
    const float* gat2_Wr = (const float*)d_in[32];
    const float* gat2_br = (const float*)d_in[33];
    const float* gat2_att = (const float*)d_in[34];
    const float* gat2_bias = (const float*)d_in[35];
    const float* bn4_g = (const float*)d_in[36];
    const float* bn4_b = (const float*)d_in[37];
    const float* fc_W = (const float*)d_in[38];
    const float* fc_b = (const float*)d_in[39];
    float* out = (float*)d_out;

    const size_t NEEDED = 194682880ull;
    if (ws_size < NEEDED) {
        zero_out<<<(BG + 255) / 256, 256, 0, stream>>>(out, BG);
        return;
    }
    char* w = (char*)d_ws;
    __hip_bfloat16* H = (__hip_bfloat16*)w;
    __hip_bfloat16* CG = (__hip_bfloat16*)w;
    __hip_bfloat16* A2 = (__hip_bfloat16*)(w + 102400000);   // ping-pong pair base
    __hip_bfloat16* GW12 = (__hip_bfloat16*)(w + 117440512);
    __hip_bfloat16* GW34 = (__hip_bfloat16*)(w + 121634816);
    __hip_bfloat16* Z1B = (__hip_bfloat16*)(w + 125829120);
    float* B12 = (float*)(w + 140509184);
    float* B34 = (float*)(w + 140525568);

    char* C = w + 161120256;
    __hip_bfloat16* XIN = (__hip_bfloat16*)C;
    __hip_bfloat16* XNB = (__hip_bfloat16*)C;
    __hip_bfloat16* Z2B = (__hip_bfloat16*)(C + 14680064);
    int* ROWPTR = (int*)(C + 14680064);
    int* CURSOR = (int*)(C + 15080192);
    int* EID = (int*)(C + 15480320);
    int* DEG = (int*)(C + 16280320);
    __hip_bfloat16* G1W = (__hip_bfloat16*)(C + 16680320);
    __hip_bfloat16* G2W = (__hip_bfloat16*)(C + 16745856);
    int* BSUM = (int*)(C + 17270144);

    float* PS = (float*)(w + 190480384);
    float* PC = (float*)(w + 194674688);

    const int* src = eidx;
    const int* dst = eidx + N_EDGESC;

    // ---- CSR build ----
    zero_int<<<(N_NODESC + 255) / 256, 256, 0, stream>>>(DEG, N_NODESC);
    zero_f4<<<(BG * 512 / 4 + 255) / 256, 256, 0, stream>>>((float4*)PS, BG * 512 / 4);
    zero_f4<<<(BG / 4 + 255) / 256, 256, 0, stream>>>((float4*)PC, BG / 4);
    hist_dst<<<(N_EDGESC + 255) / 256, 256, 0, stream>>>(dst, DEG);
    const int NB = (N_NODESC + 1023) / 1024;  // 98
    scan_bsums<<<NB, 256, 0, stream>>>(DEG, BSUM, N_NODESC);
    scan_top<<<1, 64, 0, stream>>>(BSUM, NB, ROWPTR + N_NODESC);
    scan_final<<<NB, 256, 0, stream>>>(DEG, BSUM, ROWPTR, CURSOR, N_NODESC);
    scatter_eid<<<(N_EDGESC + 255) / 256, 256, 0, stream>>>(dst, CURSOR, EID);

    // ---- GINE weight prep ----
    transpose_w<<<dim3(1, 8), 256, 0, stream>>>(g1_W, G1W, 64, 512);
    transpose_w<<<dim3(8, 8), 256, 0, stream>>>(g2_W, G2W, 512, 512);

    // ---- GINE1 ----
    gine1_gather<<<(N_NODESC + 4 * G1_NPW - 1) / (4 * G1_NPW), 256, 0, stream>>>(
        x, src, eattr, e1_W, e1_b, ROWPTR, EID, XIN);
    mfma_gemm<1><<<dim3(4, (N_NODESC + 127) / 128), 256, 0, stream>>>(
        XIN, G1W, N_NODESC, 64, 512, g1_b, bn1_g, bn1_b, nullptr, nullptr, H);
    count_nodes<<<(N_NODESC + 255) / 256, 256, 0, stream>>>(batch, PC);

    // ---- GINE2: 4 chunks of 25k, gemm(c) overlapped with gather(c+1) ----
    {
        const int GY = (G2CH + 127) / 128;            // 196
        const int GG = 4 * GY;                        // 784 gemm blocks
        const int NGB = (G2CH + G2_NPB - 1) / G2_NPB; // 3125 gather blocks
        __hip_bfloat16* A2b[2] = {A2, A2 + (size_t)G2CH * 512};
        gine2_gather<<<NGB, 256, 0, stream>>>(H, src, eattr, e2_W, e2_b,
                                              ROWPTR, EID, A2b[0], 0, G2CH);
        for (int c = 0; c < 4; c++) {
            int c0n = c * G2CH;
            if (c < 3) {
                gine2_fused<<<5 * GG, 256, 0, stream>>>(
                    H, src, eattr, e2_W, e2_b, ROWPTR, EID,
                    A2b[c & 1], A2b[(c + 1) & 1],
                    G2W, g2_b, bn2_g, bn2_b, batch + c0n, PS,
                    G2CH, GY, (c + 1) * G2CH, (c + 2) * G2CH, NGB);
            } else {
                mfma_gemm<2><<<dim3(4, GY), 256, 0, stream>>>(
                    A2b[c & 1], G2W, G2CH, 512, 512, g2_b, bn2_g, bn2_b,
                    batch + c0n, PS, nullptr);
            }
        }
    }

    // ---- GAT weight prep (H and A2 dead) ----
    transpose_w<<<dim3(8, 32), 256, 0, stream>>>(gat1_Wl, GW12, 512, 2048);
    transpose_w<<<dim3(8, 32), 256, 0, stream>>>(gat1_Wr, GW12 + (size_t)2048 * 512, 512, 2048);
    transpose_w<<<dim3(8, 32), 256, 0, stream>>>(gat2_Wl, GW34, 512, 2048);
    transpose_w<<<dim3(8, 32), 256, 0, stream>>>(gat2_Wr, GW34 + (size_t)2048 * 512, 512, 2048);
    concat_bias<<<8, 256, 0, stream>>>(gat1_bl, gat1_br, B12);
    concat_bias<<<8, 256, 0, stream>>>(gat2_bl, gat2_br, B34);

    // ---- pool -> xn ----
    build_xn<<<(BG * 512) / 256, 256, 0, stream>>>(PS, PC, ecfp, topo, maccs, estate,
                                                   rdkit2d, phar2d, XNB);
    // ---- GAT layer 1 (fused L|R: N = 4096) ----
    const int MGAT = BG * 7;  // 14336
    dim3 ggrid(4096 / 128, MGAT / 128);
    mfma_gemm<0><<<ggrid, 256, 0, stream>>>(XNB, GW12, MGAT, 512, 4096, B12,
                                            nullptr, nullptr, nullptr, nullptr, CG);
    gat_attn<<<BG, 256, 0, stream>>>(CG, gat1_att, gat1_bias, bn3_g, bn3_b, Z1B);
    // ---- GAT layer 2 ----
    mfma_gemm<0><<<ggrid, 256, 0, stream>>>(Z1B, GW34, MGAT, 512, 4096, B34,
                                            nullptr, nullptr, nullptr, nullptr, CG);
    gat_attn<<<BG, 256, 0, stream>>>(CG, gat2_att, gat2_bias, bn4_g, bn4_b, Z2B);
    // ---- final fc ----
    final_fc<<<BG / 4, 256, 0, stream>>>(Z2B, fc_W, fc_b, out);
}

// Round 10
// 848.488 us; speedup vs baseline: 1.1482x; 1.1482x over previous
//
#include <hip/hip_runtime.h>
#include <hip/hip_bf16.h>

#define N_NODESC 100000
#define N_EDGESC 200000
#define BG 2048
#define NDIM 64
#define EDIM 16

typedef __bf16 bf16x8 __attribute__((ext_vector_type(8)));
typedef float f32x4 __attribute__((ext_vector_type(4)));

static __device__ __forceinline__ float bn_inv() { return 0.9999950000374997f; }

static __device__ __forceinline__ float b2f(short s) {
    __hip_bfloat16 h = *(const __hip_bfloat16*)&s;
    return __bfloat162float(h);
}

// async global->LDS 16B per lane; LDS dest = wave-uniform base + lane*16
__device__ __forceinline__ void gl2lds16(const void* g, void* l) {
    __builtin_amdgcn_global_load_lds(
        (const __attribute__((address_space(1))) unsigned int*)g,
        (__attribute__((address_space(3))) unsigned int*)l, 16, 0, 0);
}

// ---------------- zero fills --------------------------------------------------
__global__ void zero_f4(float4* __restrict__ p, int n4) {
    int i = blockIdx.x * 256 + threadIdx.x;
    if (i < n4) p[i] = make_float4(0.f, 0.f, 0.f, 0.f);
}
__global__ void zero_int(int* __restrict__ p, int n) {
    int i = blockIdx.x * 256 + threadIdx.x;
    if (i < n) p[i] = 0;
}
__global__ void zero_out(float* __restrict__ p, int n) {
    int i = blockIdx.x * 256 + threadIdx.x;
    if (i < n) p[i] = 0.f;
}

// ---------------- CSR build: histogram -> scan -> scatter --------------------
__global__ void hist_dst(const int* __restrict__ dst, int* __restrict__ deg) {
    int i = blockIdx.x * 256 + threadIdx.x;
    if (i < N_EDGESC) atomicAdd(&deg[dst[i]], 1);
}
__global__ void scan_bsums(const int* __restrict__ deg, int* __restrict__ bsum, int n) {
    __shared__ int ls[256];
    int b = blockIdx.x, t = threadIdx.x;
    int s = 0;
#pragma unroll
    for (int j = 0; j < 4; j++) {
        int i = b * 1024 + t * 4 + j;
        if (i < n) s += deg[i];
    }
    ls[t] = s;
    __syncthreads();
    for (int off = 128; off; off >>= 1) {
        if (t < off) ls[t] += ls[t + off];
        __syncthreads();
    }
    if (t == 0) bsum[b] = ls[0];
}
__global__ void scan_top(int* __restrict__ bsum, int nb, int* __restrict__ total) {
    if (threadIdx.x == 0) {
        int acc = 0;
        for (int i = 0; i < nb; i++) { int v = bsum[i]; bsum[i] = acc; acc += v; }
        *total = acc;
    }
}
__global__ void scan_final(const int* __restrict__ deg, const int* __restrict__ bsum,
                           int* __restrict__ rowptr, int* __restrict__ cursor, int n) {
    __shared__ int ls[256];
    int b = blockIdx.x, t = threadIdx.x;
    int v[4], s = 0;
#pragma unroll
    for (int j = 0; j < 4; j++) {
        int i = b * 1024 + t * 4 + j;
        v[j] = (i < n) ? deg[i] : 0;
        s += v[j];
    }
    ls[t] = s;
    __syncthreads();
    int run = s;
    for (int off = 1; off < 256; off <<= 1) {
        int add = (t >= off) ? ls[t - off] : 0;
        __syncthreads();
        ls[t] += add;
        __syncthreads();
    }
    int excl = ls[t] - run + bsum[b];
#pragma unroll
    for (int j = 0; j < 4; j++) {
        int i = b * 1024 + t * 4 + j;
        if (i < n) { rowptr[i] = excl; cursor[i] = excl; excl += v[j]; }
    }
}
__global__ void scatter_eid(const int* __restrict__ dst, int* __restrict__ cursor,
                            int* __restrict__ eid) {
    int e = blockIdx.x * 256 + threadIdx.x;
    if (e < N_EDGESC) {
        int p = atomicAdd(&cursor[dst[e]], 1);
        eid[p] = e;
    }
}

// ---------------- W [K][N] f32 -> bf16 [N][K] --------------------------------
__global__ void transpose_w(const float* __restrict__ W, __hip_bfloat16* __restrict__ hi,
                            int K, int N) {
    __shared__ float t[64][65];
    int k0 = blockIdx.x * 64, n0 = blockIdx.y * 64;
    int tid = threadIdx.x, tx = tid & 63, ty = tid >> 6;
    for (int r = ty; r < 64; r += 4) t[r][tx] = W[(size_t)(k0 + r) * N + n0 + tx];
    __syncthreads();
    for (int r = ty; r < 64; r += 4)
        hi[(size_t)(n0 + r) * K + k0 + tx] = __float2bfloat16(t[tx][r]);
}

__global__ void concat_bias(const float* __restrict__ a, const float* __restrict__ b,
                            float* __restrict__ o) {
    int i = blockIdx.x * 256 + threadIdx.x;
    if (i < 2048) { o[i] = a[i]; o[2048 + i] = b[i]; }
}

// ---------------- GINE1 gather -----------------------------------------------
// Round-9/10: launch_bounds (256,2) -> (256,6). Same latency-bound shape as
// the round-3 gine2 case (dependent eid->src->x[s] chain); ~36 VGPR fits the
// 6-waves/SIMD budget (<=80) without spill -> 3x wave supply.
#define G1_NPW 8
__global__ __launch_bounds__(256, 6) void gine1_gather(
    const float* __restrict__ x, const int* __restrict__ srcv, const float* __restrict__ ea,
    const float* __restrict__ e1W, const float* __restrict__ e1b,
    const int* __restrict__ rowptr, const int* __restrict__ eid,
    __hip_bfloat16* __restrict__ xin) {
    int tid = threadIdx.x;
    int wave = tid >> 6, lane = tid & 63;
    float wreg[16];
#pragma unroll
    for (int k = 0; k < 16; k++) wreg[k] = e1W[k * 64 + lane];
    float bb = e1b[lane];
    int nbase = (blockIdx.x * 4 + wave) * G1_NPW;
#pragma unroll 1
    for (int it = 0; it < G1_NPW; it++) {
        int n = nbase + it;
        if (n >= N_NODESC) return;
        float acc = x[(size_t)n * 64 + lane];
        int beg = rowptr[n], end = rowptr[n + 1];
        for (int idx = beg; idx < end; idx++) {
            int e = eid[idx], s = srcv[e];
            const float4* ef = (const float4*)(ea + (size_t)e * 16);
            float4 e0 = ef[0], e1 = ef[1], e2 = ef[2], e3 = ef[3];
            float p = bb;
            p = fmaf(e0.x, wreg[0], p);  p = fmaf(e0.y, wreg[1], p);
            p = fmaf(e0.z, wreg[2], p);  p = fmaf(e0.w, wreg[3], p);
            p = fmaf(e1.x, wreg[4], p);  p = fmaf(e1.y, wreg[5], p);
            p = fmaf(e1.z, wreg[6], p);  p = fmaf(e1.w, wreg[7], p);
            p = fmaf(e2.x, wreg[8], p);  p = fmaf(e2.y, wreg[9], p);
            p = fmaf(e2.z, wreg[10], p); p = fmaf(e2.w, wreg[11], p);
            p = fmaf(e3.x, wreg[12], p); p = fmaf(e3.y, wreg[13], p);
            p = fmaf(e3.z, wreg[14], p); p = fmaf(e3.w, wreg[15], p);
            acc += fmaxf(x[(size_t)s * 64 + lane] + p, 0.f);
        }
        xin[(size_t)n * 64 + lane] = __float2bfloat16(acc);
    }
}

// ---------------- GINE2 gather -----------------------------------------------
// Round-3 structure (confirmed win): block per node, 2 cols/thread,
// launch_bounds(256,5), 2-edge-unrolled inner loop for MLP.
// Round-8 fusion with the GEMM REGRESSED (33KB LDS + bounds(256,4) on gather
// blocks killed the gather's occupancy) -- keep standalone.
#define G2_NPB 8
__global__ __launch_bounds__(256, 5) void gine2_gather(
    const __hip_bfloat16* __restrict__ h, const int* __restrict__ srcv,
    const float* __restrict__ ea, const float* __restrict__ e2W,
    const float* __restrict__ e2b, const int* __restrict__ rowptr,
    const int* __restrict__ eid, __hip_bfloat16* __restrict__ a2, int n0, int n1) {
    int tid = threadIdx.x;
    int c0 = tid * 2;
    float wreg[2][16], breg[2];
#pragma unroll
    for (int j = 0; j < 2; j++) {
        breg[j] = e2b[c0 + j];
#pragma unroll
        for (int k = 0; k < 16; k++) wreg[j][k] = e2W[k * 512 + c0 + j];
    }
    int nbase = n0 + blockIdx.x * G2_NPB;
#pragma unroll 1
    for (int it = 0; it < G2_NPB; it++) {
        int n = nbase + it;
        if (n >= n1) return;
        unsigned int hv = *(const unsigned int*)((const short*)(h + (size_t)n * 512) + c0);
        const __hip_bfloat16* hb = (const __hip_bfloat16*)&hv;
        float acc[2] = {__bfloat162float(hb[0]), __bfloat162float(hb[1])};
        int beg = rowptr[n], end = rowptr[n + 1];
        int idx = beg;
#pragma unroll 1
        for (; idx + 2 <= end; idx += 2) {
            int ei0 = eid[idx], ei1 = eid[idx + 1];
            int s0 = srcv[ei0], s1 = srcv[ei1];
            const float4* ef0 = (const float4*)(ea + (size_t)ei0 * 16);
            const float4* ef1 = (const float4*)(ea + (size_t)ei1 * 16);
            float4 a0 = ef0[0], a1 = ef0[1], a2v = ef0[2], a3 = ef0[3];
            float4 b0 = ef1[0], b1 = ef1[1], b2v = ef1[2], b3 = ef1[3];
            unsigned int sv0 = *(const unsigned int*)((const short*)(h + (size_t)s0 * 512) + c0);
            unsigned int sv1 = *(const unsigned int*)((const short*)(h + (size_t)s1 * 512) + c0);
            const __hip_bfloat16* sb0 = (const __hip_bfloat16*)&sv0;
            const __hip_bfloat16* sb1 = (const __hip_bfloat16*)&sv1;
#pragma unroll
            for (int j = 0; j < 2; j++) {
                float p = breg[j];
                p = fmaf(a0.x, wreg[j][0], p);  p = fmaf(a0.y, wreg[j][1], p);
                p = fmaf(a0.z, wreg[j][2], p);  p = fmaf(a0.w, wreg[j][3], p);
                p = fmaf(a1.x, wreg[j][4], p);  p = fmaf(a1.y, wreg[j][5], p);
                p = fmaf(a1.z, wreg[j][6], p);  p = fmaf(a1.w, wreg[j][7], p);
                p = fmaf(a2v.x, wreg[j][8], p); p = fmaf(a2v.y, wreg[j][9], p);
                p = fmaf(a2v.z, wreg[j][10], p);p = fmaf(a2v.w, wreg[j][11], p);
                p = fmaf(a3.x, wreg[j][12], p); p = fmaf(a3.y, wreg[j][13], p);
                p = fmaf(a3.z, wreg[j][14], p); p = fmaf(a3.w, wreg[j][15], p);
                acc[j] += fmaxf(__bfloat162float(sb0[j]) + p, 0.f);
                float q = breg[j];
                q = fmaf(b0.x, wreg[j][0], q);  q = fmaf(b0.y, wreg[j][1], q);
                q = fmaf(b0.z, wreg[j][2], q);  q = fmaf(b0.w, wreg[j][3], q);
                q = fmaf(b1.x, wreg[j][4], q);  q = fmaf(b1.y, wreg[j][5], q);
                q = fmaf(b1.z, wreg[j][6], q);  q = fmaf(b1.w, wreg[j][7], q);
                q = fmaf(b2v.x, wreg[j][8], q); q = fmaf(b2v.y, wreg[j][9], q);
                q = fmaf(b2v.z, wreg[j][10], q);q = fmaf(b2v.w, wreg[j][11], q);
                q = fmaf(b3.x, wreg[j][12], q); q = fmaf(b3.y, wreg[j][13], q);
                q = fmaf(b3.z, wreg[j][14], q); q = fmaf(b3.w, wreg[j][15], q);
                acc[j] += fmaxf(__bfloat162float(sb1[j]) + q, 0.f);
            }
        }
        if (idx < end) {
            int ei = eid[idx];
            int s = srcv[ei];
            const float4* ef = (const float4*)(ea + (size_t)ei * 16);
            float4 a0 = ef[0], a1 = ef[1], a2v = ef[2], a3 = ef[3];
            unsigned int sv = *(const unsigned int*)((const short*)(h + (size_t)s * 512) + c0);
            const __hip_bfloat16* sb = (const __hip_bfloat16*)&sv;
#pragma unroll
            for (int j = 0; j < 2; j++) {
                float p = breg[j];
                p = fmaf(a0.x, wreg[j][0], p);  p = fmaf(a0.y, wreg[j][1], p);
                p = fmaf(a0.z, wreg[j][2], p);  p = fmaf(a0.w, wreg[j][3], p);
                p = fmaf(a1.x, wreg[j][4], p);  p = fmaf(a1.y, wreg[j][5], p);
                p = fmaf(a1.z, wreg[j][6], p);  p = fmaf(a1.w, wreg[j][7], p);
                p = fmaf(a2v.x, wreg[j][8], p); p = fmaf(a2v.y, wreg[j][9], p);
                p = fmaf(a2v.z, wreg[j][10], p);p = fmaf(a2v.w, wreg[j][11], p);
                p = fmaf(a3.x, wreg[j][12], p); p = fmaf(a3.y, wreg[j][13], p);
                p = fmaf(a3.z, wreg[j][14], p); p = fmaf(a3.w, wreg[j][15], p);
                acc[j] += fmaxf(__bfloat162float(sb[j]) + p, 0.f);
            }
        }
        __hip_bfloat16 o[2];
        o[0] = __float2bfloat16(acc[0]);
        o[1] = __float2bfloat16(acc[1]);
        *(unsigned int*)((short*)(a2 + (size_t)(n - n0) * 512) + c0) = *(const unsigned int*)o;
    }
}

// ---------------- MFMA GEMM: C[M,N] = A[M,K](bf16) @ B^T[N,K](bf16) ----------
// m97 schedule + T1 XCD swizzle + BK=64 + LDS-bounce epilogue (round-6) +
// MODE-2 quad-reduced atomics (round-5).
// Round-10: MODE-0 C-stores are NON-TEMPORAL (as 8-byte u64 scalars --
// __builtin_nontemporal_store rejects HIP_vector_type). CG has zero L2 reuse
// value (written once, streamed once by gat_attn) and its 114MB write stream
// was evicting the B panels (FETCH 122MB vs ~50MB ideal). MODE 1 keeps normal
// stores (H is re-read at random by gine2_gather).
// GRID: x = col-tile (fast), y = row-tile.
template <int MODE>
__global__ __launch_bounds__(256, 4) void mfma_gemm(
    const __hip_bfloat16* __restrict__ A, const __hip_bfloat16* __restrict__ Bhi,
    int M, int K, int N, const float* __restrict__ bias, const float* __restrict__ bng,
    const float* __restrict__ bnb, const int* __restrict__ batch,
    float* __restrict__ psum, __hip_bfloat16* __restrict__ Cout) {
    // 33 KB: K-loop uses [0,16384) as As[2]|Bh[2]; epilogue reuses all 16896
    // shorts as a [128][132] C-bounce tile.
    __shared__ __align__(16) short buf[16896];
    short* AsP = buf;           // As[h] = AsP + h*4096, [128][32] each
    short* BhP = buf + 8192;    // Bh[h] = BhP + h*4096

    int nwg = gridDim.x * gridDim.y;
    int wg = blockIdx.x + gridDim.x * blockIdx.y;
    int q = nwg >> 3, r = nwg & 7;
    int xcd = wg & 7, idx = wg >> 3;
    int swz = (xcd < r) ? (xcd * (q + 1) + idx)
                        : (r * (q + 1) + (xcd - r) * q + idx);
    int bx = swz % gridDim.x, by = swz / gridDim.x;

    int r0 = by * 128;
    int n0 = bx * 128;
    int tid = threadIdx.x;
    int lane = tid & 63;
    int wv = tid >> 6;
    int wm = (wv >> 1) * 64, wn = (wv & 1) * 64;

    f32x4 acc[4][4];
#pragma unroll
    for (int i = 0; i < 4; i++)
#pragma unroll
        for (int j = 0; j < 4; j++) acc[i][j] = (f32x4){0.f, 0.f, 0.f, 0.f};

    // staging indices: linear i in [0,512), row = i>>2, kb = i&3; LDS offset = i*16B
    int rowA0 = tid >> 2, cbA0 = tid & 3;
    int rowA1 = (tid + 256) >> 2;  // (tid+256)&3 == tid&3
    int gA0 = r0 + rowA0; if (gA0 >= M) gA0 = M - 1;
    int gA1 = r0 + rowA1; if (gA1 >= M) gA1 = M - 1;
    const __hip_bfloat16* pA0 = A + (size_t)gA0 * K + cbA0 * 8;
    const __hip_bfloat16* pA1 = A + (size_t)gA1 * K + cbA0 * 8;
    const __hip_bfloat16* pB0 = Bhi + (size_t)(n0 + rowA0) * K + cbA0 * 8;
    const __hip_bfloat16* pB1 = Bhi + (size_t)(n0 + rowA1) * K + cbA0 * 8;

    int fi = lane & 15, kb = (lane >> 4) * 8;
    for (int k0 = 0; k0 < K; k0 += 64) {
        __syncthreads();
        // stage BOTH 32-wide halves before one drain (8 gl2lds16/thread)
#pragma unroll
        for (int hh = 0; hh < 2; hh++) {
            int kk = k0 + hh * 32;
            gl2lds16(pA0 + kk, AsP + hh * 4096 + wv * 512);
            gl2lds16(pA1 + kk, AsP + hh * 4096 + 2048 + wv * 512);
            gl2lds16(pB0 + kk, BhP + hh * 4096 + wv * 512);
            gl2lds16(pB1 + kk, BhP + hh * 4096 + 2048 + wv * 512);
        }
        __syncthreads();
#pragma unroll
        for (int ks = 0; ks < 2; ks++) {
            bf16x8 af[4], bhf[4];
#pragma unroll
            for (int mi = 0; mi < 4; mi++)
                af[mi] = *(const bf16x8*)(AsP + ks * 4096 + (wm + mi * 16 + fi) * 32 + kb);
#pragma unroll
            for (int ni = 0; ni < 4; ni++)
                bhf[ni] = *(const bf16x8*)(BhP + ks * 4096 + (wn + ni * 16 + fi) * 32 + kb);
#pragma unroll
            for (int mi = 0; mi < 4; mi++)
#pragma unroll
                for (int ni = 0; ni < 4; ni++)
                    acc[mi][ni] = __builtin_amdgcn_mfma_f32_16x16x32_bf16(
                        af[mi], bhf[ni], acc[mi][ni], 0, 0, 0);
        }
    }
    int col_l = lane & 15, quad = lane >> 4;
    if (MODE == 0 || MODE == 1) {
        // ---- LDS-bounce epilogue: fragments -> [128][132] tile -> wide stores
        __syncthreads();  // all K-loop ds_reads complete before overwriting buf
#pragma unroll
        for (int mi = 0; mi < 4; mi++) {
            int rloc = wm + mi * 16 + quad * 4;
#pragma unroll
            for (int ni = 0; ni < 4; ni++) {
                int cloc = wn + ni * 16 + col_l;
                float b0 = bias[n0 + cloc];
                float g0 = 0.f, bb0 = 0.f;
                if (MODE == 1) { g0 = bng[n0 + cloc]; bb0 = bnb[n0 + cloc]; }
#pragma unroll
                for (int reg = 0; reg < 4; reg++) {
                    float v = acc[mi][ni][reg] + b0;
                    if (MODE == 1) v = fmaxf(fmaf(v * bn_inv(), g0, bb0), 0.f);
                    __hip_bfloat16 hv = __float2bfloat16(v);
                    buf[(rloc + reg) * 132 + cloc] = *(const short*)&hv;
                }
            }
        }
        __syncthreads();
        // stream out: 8 rows per pass (32 lanes x 8B = 256B/row, full lines)
#pragma unroll
        for (int p = 0; p < 16; p++) {
            int row = p * 8 + (tid >> 5);
            int grow = r0 + row;
            if (grow < M) {
                int c4 = (tid & 31) * 4;
                unsigned long long v = *(const unsigned long long*)(buf + row * 132 + c4);
                unsigned long long* dst =
                    (unsigned long long*)(Cout + (size_t)grow * N + n0 + c4);
                if (MODE == 0) __builtin_nontemporal_store(v, dst);
                else *dst = v;
            }
        }
    } else {
#pragma unroll
        for (int mi = 0; mi < 4; mi++) {
            int rbase = r0 + wm + mi * 16 + quad * 4;
#pragma unroll
            for (int ni = 0; ni < 4; ni++) {
                int gcol = n0 + wn + ni * 16 + col_l;
                float b0 = bias[gcol], g0 = bng[gcol], bb0 = bnb[gcol];
                float vv[4];
#pragma unroll
                for (int reg = 0; reg < 4; reg++)
                    vv[reg] = fmaxf(fmaf((acc[mi][ni][reg] + b0) * bn_inv(), g0, bb0), 0.f);
                // rows covered by this wave's mi: rtop .. rtop+15 (wave-uniform)
                int rtop = r0 + wm + mi * 16;
                bool uni16 = (rtop + 15 < M) && (batch[rtop] == batch[rtop + 15]);
                float vs = (vv[0] + vv[1]) + (vv[2] + vv[3]);
                if (uni16) {
                    // sum the 4 quads' 4-row partials: lanes ^16, ^32 keep col_l
                    vs += __shfl_xor(vs, 16);
                    vs += __shfl_xor(vs, 32);
                    if (quad == 0)
                        atomicAdd(&psum[(size_t)batch[rtop] * 512 + gcol], vs);
                } else if (rbase + 3 < M && batch[rbase] == batch[rbase + 3]) {
                    atomicAdd(&psum[(size_t)batch[rbase] * 512 + gcol], vs);
                } else {
#pragma unroll
                    for (int reg = 0; reg < 4; reg++) {
                        int grow = rbase + reg;
                        if (grow < M)
                            atomicAdd(&psum[(size_t)batch[grow] * 512 + gcol], vv[reg]);
                    }
                }
            }
        }
    }
}

// ---------------- node counts per graph --------------------------------------
__global__ void count_nodes(const int* __restrict__ batch, float* __restrict__ cnt) {
    int i = blockIdx.x * 256 + threadIdx.x;
    if (i < N_NODESC) atomicAdd(&cnt[batch[i]], 1.0f);
}

// ---------------- finalize pool + assemble xn [B,7,512] bf16 -----------------
__global__ void build_xn(const float* __restrict__ psum, const float* __restrict__ cnt,
                         const float* __restrict__ ecfp, const float* __restrict__ topo,
                         const float* __restrict__ maccs, const float* __restrict__ estate,
                         const float* __restrict__ rdkit2d, const float* __restrict__ phar2d,
                         __hip_bfloat16* __restrict__ xn) {
    int i = blockIdx.x * 256 + threadIdx.x;
    if (i >= BG * 512) return;
    int bidx = i >> 9, c = i & 511;
    float cv = fmaxf(cnt[bidx], 1.0f);
    __hip_bfloat16* o = xn + (size_t)bidx * 7 * 512;
    o[c] = __float2bfloat16(psum[i] / cv);
    o[512 + c] = __float2bfloat16(ecfp[i]);
    o[2 * 512 + c] = __float2bfloat16(topo[i]);
    o[3 * 512 + c] = __float2bfloat16(maccs[i]);
    o[4 * 512 + c] = __float2bfloat16(estate[i]);
    o[5 * 512 + c] = __float2bfloat16(rdkit2d[i]);
    o[6 * 512 + c] = __float2bfloat16(phar2d[i]);
}

// ---------------- GAT attention (fused gl|gr layout: C[B*7][4096]) -----------
// Round-7: vectorized (G13) -- short4 loads in both phases.
__global__ void gat_attn(const __hip_bfloat16* __restrict__ cg,
                         const float* __restrict__ att, const float* __restrict__ bias,
                         const float* __restrict__ bng, const float* __restrict__ bnb,
                         __hip_bfloat16* __restrict__ zout) {
    int b = blockIdx.x;
    int tid = threadIdx.x;
    int wave = tid >> 6, lane = tid & 63;
    __shared__ float logits[13][4];
    __shared__ float alpha[13][4];
    const size_t base = (size_t)b * 7 * 4096;
    for (int p = wave; p < 52; p += 4) {
        int e = p >> 2, hh = p & 3;
        int se = (e < 7) ? 0 : (e - 6);
        int de = (e < 6) ? (e + 1) : ((e == 6) ? 0 : (e - 6));
        const short* glp = (const short*)(cg + base + (size_t)se * 4096 + hh * 512) + lane * 8;
        const short* grp = (const short*)(cg + base + (size_t)de * 4096 + 2048 + hh * 512) + lane * 8;
        short4 gl0 = ((const short4*)glp)[0], gl1 = ((const short4*)glp)[1];
        short4 gr0 = ((const short4*)grp)[0], gr1 = ((const short4*)grp)[1];
        const float4* ap = (const float4*)(att + hh * 512 + lane * 8);
        float4 a0 = ap[0], a1 = ap[1];
        float s = 0.f, v;
        v = b2f(gl0.x) + b2f(gr0.x); v = (v >= 0.f) ? v : 0.2f * v; s = fmaf(v, a0.x, s);
        v = b2f(gl0.y) + b2f(gr0.y); v = (v >= 0.f) ? v : 0.2f * v; s = fmaf(v, a0.y, s);
        v = b2f(gl0.z) + b2f(gr0.z); v = (v >= 0.f) ? v : 0.2f * v; s = fmaf(v, a0.z, s);
        v = b2f(gl0.w) + b2f(gr0.w); v = (v >= 0.f) ? v : 0.2f * v; s = fmaf(v, a0.w, s);
        v = b2f(gl1.x) + b2f(gr1.x); v = (v >= 0.f) ? v : 0.2f * v; s = fmaf(v, a1.x, s);
        v = b2f(gl1.y) + b2f(gr1.y); v = (v >= 0.f) ? v : 0.2f * v; s = fmaf(v, a1.y, s);
        v = b2f(gl1.z) + b2f(gr1.z); v = (v >= 0.f) ? v : 0.2f * v; s = fmaf(v, a1.z, s);
        v = b2f(gl1.w) + b2f(gr1.w); v = (v >= 0.f) ? v : 0.2f * v; s = fmaf(v, a1.w, s);
#pragma unroll
        for (int off = 32; off; off >>= 1) s += __shfl_down(s, off);
        if (lane == 0) logits[e][hh] = s;
    }
    __syncthreads();
    if (tid < 24) {
        int n = 1 + (tid >> 2), hh = tid & 3;
        float la = logits[n - 1][hh], lb = logits[6 + n][hh];
        float m = fmaxf(la, lb);
        float ea = __expf(la - m), eb = __expf(lb - m);
        float inv = 1.f / (ea + eb);
        alpha[n - 1][hh] = ea * inv;
        alpha[6 + n][hh] = eb * inv;
    } else if (tid < 28) {
        alpha[6][tid & 3] = 1.f;
    }
    __syncthreads();
    // Phase 2: 7*128 units of 4 columns each
    for (int u = tid; u < 7 * 128; u += 256) {
        int n = u >> 7, c4 = (u & 127) * 4;
        float v0 = 0.f, v1 = 0.f, v2 = 0.f, v3 = 0.f;
        const short* g0 = (const short*)(cg + base) + c4;
        if (n == 0) {
#pragma unroll
            for (int hh = 0; hh < 4; hh++) {
                short4 t = *(const short4*)(g0 + hh * 512);
                float a = alpha[6][hh];
                v0 = fmaf(a, b2f(t.x), v0); v1 = fmaf(a, b2f(t.y), v1);
                v2 = fmaf(a, b2f(t.z), v2); v3 = fmaf(a, b2f(t.w), v3);
            }
        } else {
            const short* gn = (const short*)(cg + base + (size_t)n * 4096) + c4;
#pragma unroll
            for (int hh = 0; hh < 4; hh++) {
                short4 t = *(const short4*)(g0 + hh * 512);
                float a = alpha[n - 1][hh];
                v0 = fmaf(a, b2f(t.x), v0); v1 = fmaf(a, b2f(t.y), v1);
                v2 = fmaf(a, b2f(t.z), v2); v3 = fmaf(a, b2f(t.w), v3);
                short4 t2 = *(const short4*)(gn + hh * 512);
                float a2 = alpha[6 + n][hh];
                v0 = fmaf(a2, b2f(t2.x), v0); v1 = fmaf(a2, b2f(t2.y), v1);
                v2 = fmaf(a2, b2f(t2.z), v2); v3 = fmaf(a2, b2f(t2.w), v3);
            }
        }
        float4 bi = *(const float4*)(bias + c4);
        float4 gg = *(const float4*)(bng + c4);
        float4 bb = *(const float4*)(bnb + c4);
        v0 = fmaxf(fmaf(fmaf(v0, 0.25f, bi.x) * bn_inv(), gg.x, bb.x), 0.f);
        v1 = fmaxf(fmaf(fmaf(v1, 0.25f, bi.y) * bn_inv(), gg.y, bb.y), 0.f);
        v2 = fmaxf(fmaf(fmaf(v2, 0.25f, bi.z) * bn_inv(), gg.z, bb.z), 0.f);
        v3 = fmaxf(fmaf(fmaf(v3, 0.25f, bi.w) * bn_inv(), gg.w, bb.w), 0.f);
        __hip_bfloat16 o[4];
        o[0] = __float2bfloat16(v0); o[1] = __float2bfloat16(v1);
        o[2] = __float2bfloat16(v2); o[3] = __float2bfloat16(v3);
        *(short4*)((short*)(zout + (size_t)b * 7 * 512) + n * 512 + c4) = *(const short4*)o;
    }
}

// ---------------- final fc ----------------------------------------------------
__global__ void final_fc(const __hip_bfloat16* __restrict__ z, const float* __restrict__ fcW,
                         const float* __restrict__ fcb, float* __restrict__ out) {
    int b = blockIdx.x * 4 + (threadIdx.x >> 6);
    int lane = threadIdx.x & 63;
    if (b >= BG) return;
    const __hip_bfloat16* row = z + (size_t)b * 7 * 512;
    float s = 0.f;
#pragma unroll
    for (int j = 0; j < 8; j++)
        s = fmaf(__bfloat162float(row[lane + j * 64]), fcW[lane + j * 64], s);
#pragma unroll
    for (int off = 32; off; off >>= 1) s += __shfl_down(s, off);
    if (lane == 0) out[b] = s + fcb[0];
}

extern "C" void kernel_launch(void* const* d_in, const int* in_sizes, int n_in,
                              void* d_out, int out_size, void* d_ws, size_t ws_size,
                              hipStream_t stream) {
    const float* x = (const float*)d_in[0];
    const int* eidx = (const int*)d_in[1];
    const float* eattr = (const float*)d_in[2];
    const int* batch = (const int*)d_in[3];
    const float* ecfp = (const float*)d_in[4];
    const float* topo = (const float*)d_in[5];
    const float* maccs = (const float*)d_in[6];
    const float* estate = (const float*)d_in[7];
    const float* rdkit2d = (const float*)d_in[8];
    const float* phar2d = (const float*)d_in[9];
    const float* g1_W = (const float*)d_in[10];
    const float* g1_b = (const float*)d_in[11];
    const float* e1_W = (const float*)d_in[12];
    const float* e1_b = (const float*)d_in[13];
    const float* bn1_g = (const float*)d_in[14];
    const float* bn1_b = (const float*)d_in[15];
    const float* g2_W = (const float*)d_in[16];
    const float* g2_b = (const float*)d_in[17];
    const float* e2_W = (const float*)d_in[18];
    const float* e2_b = (const float*)d_in[19];
    const float* bn2_g = (const float*)d_in[20];
    const float* bn2_b = (const float*)d_in[21];
    const float* gat1_Wl = (const float*)d_in[22];
    const float* gat1_bl = (const float*)d_in[23];
    const float* gat1_Wr = (const float*)d_in[24];
    const float* gat1_br = (const float*)d_in[25];
    const float* gat1_att = (const float*)d_in[26];
    const float* gat1_bias = (const float*)d_in[27];
    const float* bn3_g = (const float*)d_in[28];
    const float* bn3_b = (const float*)d_in[29];
    const float* gat2_Wl = (const float*)d_in[30];
    const float* gat2_bl = (const float*)d_in[31];
    const float* gat2_Wr = (const float*)d_in[32];
    const float* gat2_br = (const float*)d_in[33];
    const float* gat2_att = (const float*)d_in[34];
    const float* gat2_bias = (const float*)d_in[35];
    const float* bn4_g = (const float*)d_in[36];
    const float* bn4_b = (const float*)d_in[37];
    const float* fc_W = (const float*)d_in[38];
    const float* fc_b = (const float*)d_in[39];
    float* out = (float*)d_out;

    const size_t NEEDED = 194682880ull;
    if (ws_size < NEEDED) {
        zero_out<<<(BG + 255) / 256, 256, 0, stream>>>(out, BG);
        return;
    }
    char* w = (char*)d_ws;
    __hip_bfloat16* H = (__hip_bfloat16*)w;
    __hip_bfloat16* CG = (__hip_bfloat16*)w;
    __hip_bfloat16* A2 = (__hip_bfloat16*)(w + 102400000);
    __hip_bfloat16* GW12 = (__hip_bfloat16*)(w + 117440512);
    __hip_bfloat16* GW34 = (__hip_bfloat16*)(w + 121634816);
    __hip_bfloat16* Z1B = (__hip_bfloat16*)(w + 125829120);
    float* B12 = (float*)(w + 140509184);
    float* B34 = (float*)(w + 140525568);

    char* C = w + 161120256;
    __hip_bfloat16* XIN = (__hip_bfloat16*)C;
    __hip_bfloat16* XNB = (__hip_bfloat16*)C;
    __hip_bfloat16* Z2B = (__hip_bfloat16*)(C + 14680064);
    int* ROWPTR = (int*)(C + 14680064);
    int* CURSOR = (int*)(C + 15080192);
    int* EID = (int*)(C + 15480320);
    int* DEG = (int*)(C + 16280320);
    __hip_bfloat16* G1W = (__hip_bfloat16*)(C + 16680320);
    __hip_bfloat16* G2W = (__hip_bfloat16*)(C + 16745856);
    int* BSUM = (int*)(C + 17270144);

    float* PS = (float*)(w + 190480384);
    float* PC = (float*)(w + 194674688);

    const int* src = eidx;
    const int* dst = eidx + N_EDGESC;

    // ---- CSR build ----
    zero_int<<<(N_NODESC + 255) / 256, 256, 0, stream>>>(DEG, N_NODESC);
    zero_f4<<<(BG * 512 / 4 + 255) / 256, 256, 0, stream>>>((float4*)PS, BG * 512 / 4);
    zero_f4<<<(BG / 4 + 255) / 256, 256, 0, stream>>>((float4*)PC, BG / 4);
    hist_dst<<<(N_EDGESC + 255) / 256, 256, 0, stream>>>(dst, DEG);
    const int NB = (N_NODESC + 1023) / 1024;  // 98
    scan_bsums<<<NB, 256, 0, stream>>>(DEG, BSUM, N_NODESC);
    scan_top<<<1, 64, 0, stream>>>(BSUM, NB, ROWPTR + N_NODESC);
    scan_final<<<NB, 256, 0, stream>>>(DEG, BSUM, ROWPTR, CURSOR, N_NODESC);
    scatter_eid<<<(N_EDGESC + 255) / 256, 256, 0, stream>>>(dst, CURSOR, EID);

    // ---- GINE weight prep ----
    transpose_w<<<dim3(1, 8), 256, 0, stream>>>(g1_W, G1W, 64, 512);
    transpose_w<<<dim3(8, 8), 256, 0, stream>>>(g2_W, G2W, 512, 512);

    // ---- GINE1 ----
    gine1_gather<<<(N_NODESC + 4 * G1_NPW - 1) / (4 * G1_NPW), 256, 0, stream>>>(
        x, src, eattr, e1_W, e1_b, ROWPTR, EID, XIN);
    mfma_gemm<1><<<dim3(4, (N_NODESC + 127) / 128), 256, 0, stream>>>(
        XIN, G1W, N_NODESC, 64, 512, g1_b, bn1_g, bn1_b, nullptr, nullptr, H);
    count_nodes<<<(N_NODESC + 255) / 256, 256, 0, stream>>>(batch, PC);

    // ---- GINE2: 2 chunks of 50k nodes ----
    for (int c0n = 0; c0n < N_NODESC; c0n += 50000) {
        int c1n = c0n + 50000;
        int rows = 50000;
        gine2_gather<<<(rows + G2_NPB - 1) / G2_NPB, 256, 0, stream>>>(
            H, src, eattr, e2_W, e2_b, ROWPTR, EID, A2, c0n, c1n);
        mfma_gemm<2><<<dim3(4, (rows + 127) / 128), 256, 0, stream>>>(
            A2, G2W, rows, 512, 512, g2_b, bn2_g, bn2_b, batch + c0n, PS, nullptr);
    }

    // ---- GAT weight prep (H and A2 dead) ----
    transpose_w<<<dim3(8, 32), 256, 0, stream>>>(gat1_Wl, GW12, 512, 2048);
    transpose_w<<<dim3(8, 32), 256, 0, stream>>>(gat1_Wr, GW12 + (size_t)2048 * 512, 512, 2048);
    transpose_w<<<dim3(8, 32), 256, 0, stream>>>(gat2_Wl, GW34, 512, 2048);
    transpose_w<<<dim3(8, 32), 256, 0, stream>>>(gat2_Wr, GW34 + (size_t)2048 * 512, 512, 2048);
    concat_bias<<<8, 256, 0, stream>>>(gat1_bl, gat1_br, B12);
    concat_bias<<<8, 256, 0, stream>>>(gat2_bl, gat2_br, B34);

    // ---- pool -> xn ----
    build_xn<<<(BG * 512) / 256, 256, 0, stream>>>(PS, PC, ecfp, topo, maccs, estate,
                                                   rdkit2d, phar2d, XNB);
    // ---- GAT layer 1 (fused L|R: N = 4096) ----
    const int MGAT = BG * 7;  // 14336
    dim3 ggrid(4096 / 128, MGAT / 128);
    mfma_gemm<0><<<ggrid, 256, 0, stream>>>(XNB, GW12, MGAT, 512, 4096, B12,
                                            nullptr, nullptr, nullptr, nullptr, CG);
    gat_attn<<<BG, 256, 0, stream>>>(CG, gat1_att, gat1_bias, bn3_g, bn3_b, Z1B);
    // ---- GAT layer 2 ----
    mfma_gemm<0><<<ggrid, 256, 0, stream>>>(Z1B, GW34, MGAT, 512, 4096, B34,
                                            nullptr, nullptr, nullptr, nullptr, CG);
    gat_attn<<<BG, 256, 0, stream>>>(CG, gat2_att, gat2_bias, bn4_g, bn4_b, Z2B);
    // ---- final fc ----
    final_fc<<<BG / 4, 256, 0, stream>>>(Z2B, fc_W, fc_b, out);
}

// Round 11
// 843.253 us; speedup vs baseline: 1.1553x; 1.0062x over previous
//
#include <hip/hip_runtime.h>
#include <hip/hip_bf16.h>

#define N_NODESC 100000
#define N_EDGESC 200000
#define BG 2048
#define NDIM 64
#define EDIM 16

typedef __bf16 bf16x8 __attribute__((ext_vector_type(8)));
typedef float f32x4 __attribute__((ext_vector_type(4)));

static __device__ __forceinline__ float bn_inv() { return 0.9999950000374997f; }

static __device__ __forceinline__ float b2f(short s) {
    __hip_bfloat16 h = *(const __hip_bfloat16*)&s;
    return __bfloat162float(h);
}

// async global->LDS 16B per lane; LDS dest = wave-uniform base + lane*16
__device__ __forceinline__ void gl2lds16(const void* g, void* l) {
    __builtin_amdgcn_global_load_lds(
        (const __attribute__((address_space(1))) unsigned int*)g,
        (__attribute__((address_space(3))) unsigned int*)l, 16, 0, 0);
}

// ---------------- zero fills --------------------------------------------------
__global__ void zero_f4(float4* __restrict__ p, int n4) {
    int i = blockIdx.x * 256 + threadIdx.x;
    if (i < n4) p[i] = make_float4(0.f, 0.f, 0.f, 0.f);
}
__global__ void zero_int(int* __restrict__ p, int n) {
    int i = blockIdx.x * 256 + threadIdx.x;
    if (i < n) p[i] = 0;
}
__global__ void zero_out(float* __restrict__ p, int n) {
    int i = blockIdx.x * 256 + threadIdx.x;
    if (i < n) p[i] = 0.f;
}

// ---------------- CSR build: histogram -> scan -> scatter --------------------
__global__ void hist_dst(const int* __restrict__ dst, int* __restrict__ deg) {
    int i = blockIdx.x * 256 + threadIdx.x;
    if (i < N_EDGESC) atomicAdd(&deg[dst[i]], 1);
}
__global__ void scan_bsums(const int* __restrict__ deg, int* __restrict__ bsum, int n) {
    __shared__ int ls[256];
    int b = blockIdx.x, t = threadIdx.x;
    int s = 0;
#pragma unroll
    for (int j = 0; j < 4; j++) {
        int i = b * 1024 + t * 4 + j;
        if (i < n) s += deg[i];
    }
    ls[t] = s;
    __syncthreads();
    for (int off = 128; off; off >>= 1) {
        if (t < off) ls[t] += ls[t + off];
        __syncthreads();
    }
    if (t == 0) bsum[b] = ls[0];
}
__global__ void scan_top(int* __restrict__ bsum, int nb, int* __restrict__ total) {
    if (threadIdx.x == 0) {
        int acc = 0;
        for (int i = 0; i < nb; i++) { int v = bsum[i]; bsum[i] = acc; acc += v; }
        *total = acc;
    }
}
__global__ void scan_final(const int* __restrict__ deg, const int* __restrict__ bsum,
                           int* __restrict__ rowptr, int* __restrict__ cursor, int n) {
    __shared__ int ls[256];
    int b = blockIdx.x, t = threadIdx.x;
    int v[4], s = 0;
#pragma unroll
    for (int j = 0; j < 4; j++) {
        int i = b * 1024 + t * 4 + j;
        v[j] = (i < n) ? deg[i] : 0;
        s += v[j];
    }
    ls[t] = s;
    __syncthreads();
    int run = s;
    for (int off = 1; off < 256; off <<= 1) {
        int add = (t >= off) ? ls[t - off] : 0;
        __syncthreads();
        ls[t] += add;
        __syncthreads();
    }
    int excl = ls[t] - run + bsum[b];
#pragma unroll
    for (int j = 0; j < 4; j++) {
        int i = b * 1024 + t * 4 + j;
        if (i < n) { rowptr[i] = excl; cursor[i] = excl; excl += v[j]; }
    }
}
__global__ void scatter_eid(const int* __restrict__ dst, int* __restrict__ cursor,
                            int* __restrict__ eid) {
    int e = blockIdx.x * 256 + threadIdx.x;
    if (e < N_EDGESC) {
        int p = atomicAdd(&cursor[dst[e]], 1);
        eid[p] = e;
    }
}

// ---------------- W [K][N] f32 -> bf16 [N][K] --------------------------------
__global__ void transpose_w(const float* __restrict__ W, __hip_bfloat16* __restrict__ hi,
                            int K, int N) {
    __shared__ float t[64][65];
    int k0 = blockIdx.x * 64, n0 = blockIdx.y * 64;
    int tid = threadIdx.x, tx = tid & 63, ty = tid >> 6;
    for (int r = ty; r < 64; r += 4) t[r][tx] = W[(size_t)(k0 + r) * N + n0 + tx];
    __syncthreads();
    for (int r = ty; r < 64; r += 4)
        hi[(size_t)(n0 + r) * K + k0 + tx] = __float2bfloat16(t[tx][r]);
}

__global__ void concat_bias(const float* __restrict__ a, const float* __restrict__ b,
                            float* __restrict__ o) {
    int i = blockIdx.x * 256 + threadIdx.x;
    if (i < 2048) { o[i] = a[i]; o[2048 + i] = b[i]; }
}

// ---------------- GINE1 gather -----------------------------------------------
// Round-10: launch_bounds (256,6) -- latency-bound dependent-load chain,
// ~36 VGPR fits the 6-waves/SIMD budget without spill -> 3x wave supply.
#define G1_NPW 8
__global__ __launch_bounds__(256, 6) void gine1_gather(
    const float* __restrict__ x, const int* __restrict__ srcv, const float* __restrict__ ea,
    const float* __restrict__ e1W, const float* __restrict__ e1b,
    const int* __restrict__ rowptr, const int* __restrict__ eid,
    __hip_bfloat16* __restrict__ xin) {
    int tid = threadIdx.x;
    int wave = tid >> 6, lane = tid & 63;
    float wreg[16];
#pragma unroll
    for (int k = 0; k < 16; k++) wreg[k] = e1W[k * 64 + lane];
    float bb = e1b[lane];
    int nbase = (blockIdx.x * 4 + wave) * G1_NPW;
#pragma unroll 1
    for (int it = 0; it < G1_NPW; it++) {
        int n = nbase + it;
        if (n >= N_NODESC) return;
        float acc = x[(size_t)n * 64 + lane];
        int beg = rowptr[n], end = rowptr[n + 1];
        for (int idx = beg; idx < end; idx++) {
            int e = eid[idx], s = srcv[e];
            const float4* ef = (const float4*)(ea + (size_t)e * 16);
            float4 e0 = ef[0], e1 = ef[1], e2 = ef[2], e3 = ef[3];
            float p = bb;
            p = fmaf(e0.x, wreg[0], p);  p = fmaf(e0.y, wreg[1], p);
            p = fmaf(e0.z, wreg[2], p);  p = fmaf(e0.w, wreg[3], p);
            p = fmaf(e1.x, wreg[4], p);  p = fmaf(e1.y, wreg[5], p);
            p = fmaf(e1.z, wreg[6], p);  p = fmaf(e1.w, wreg[7], p);
            p = fmaf(e2.x, wreg[8], p);  p = fmaf(e2.y, wreg[9], p);
            p = fmaf(e2.z, wreg[10], p); p = fmaf(e2.w, wreg[11], p);
            p = fmaf(e3.x, wreg[12], p); p = fmaf(e3.y, wreg[13], p);
            p = fmaf(e3.z, wreg[14], p); p = fmaf(e3.w, wreg[15], p);
            acc += fmaxf(x[(size_t)s * 64 + lane] + p, 0.f);
        }
        xin[(size_t)n * 64 + lane] = __float2bfloat16(acc);
    }
}

// ---------------- GINE2 gather -----------------------------------------------
// Round-3 structure (confirmed win): block per node, 2 cols/thread,
// launch_bounds(256,5), 2-edge-unrolled inner loop for MLP.
#define G2_NPB 8
__global__ __launch_bounds__(256, 5) void gine2_gather(
    const __hip_bfloat16* __restrict__ h, const int* __restrict__ srcv,
    const float* __restrict__ ea, const float* __restrict__ e2W,
    const float* __restrict__ e2b, const int* __restrict__ rowptr,
    const int* __restrict__ eid, __hip_bfloat16* __restrict__ a2, int n0, int n1) {
    int tid = threadIdx.x;
    int c0 = tid * 2;
    float wreg[2][16], breg[2];
#pragma unroll
    for (int j = 0; j < 2; j++) {
        breg[j] = e2b[c0 + j];
#pragma unroll
        for (int k = 0; k < 16; k++) wreg[j][k] = e2W[k * 512 + c0 + j];
    }
    int nbase = n0 + blockIdx.x * G2_NPB;
#pragma unroll 1
    for (int it = 0; it < G2_NPB; it++) {
        int n = nbase + it;
        if (n >= n1) return;
        unsigned int hv = *(const unsigned int*)((const short*)(h + (size_t)n * 512) + c0);
        const __hip_bfloat16* hb = (const __hip_bfloat16*)&hv;
        float acc[2] = {__bfloat162float(hb[0]), __bfloat162float(hb[1])};
        int beg = rowptr[n], end = rowptr[n + 1];
        int idx = beg;
#pragma unroll 1
        for (; idx + 2 <= end; idx += 2) {
            int ei0 = eid[idx], ei1 = eid[idx + 1];
            int s0 = srcv[ei0], s1 = srcv[ei1];
            const float4* ef0 = (const float4*)(ea + (size_t)ei0 * 16);
            const float4* ef1 = (const float4*)(ea + (size_t)ei1 * 16);
            float4 a0 = ef0[0], a1 = ef0[1], a2v = ef0[2], a3 = ef0[3];
            float4 b0 = ef1[0], b1 = ef1[1], b2v = ef1[2], b3 = ef1[3];
            unsigned int sv0 = *(const unsigned int*)((const short*)(h + (size_t)s0 * 512) + c0);
            unsigned int sv1 = *(const unsigned int*)((const short*)(h + (size_t)s1 * 512) + c0);
            const __hip_bfloat16* sb0 = (const __hip_bfloat16*)&sv0;
            const __hip_bfloat16* sb1 = (const __hip_bfloat16*)&sv1;
#pragma unroll
            for (int j = 0; j < 2; j++) {
                float p = breg[j];
                p = fmaf(a0.x, wreg[j][0], p);  p = fmaf(a0.y, wreg[j][1], p);
                p = fmaf(a0.z, wreg[j][2], p);  p = fmaf(a0.w, wreg[j][3], p);
                p = fmaf(a1.x, wreg[j][4], p);  p = fmaf(a1.y, wreg[j][5], p);
                p = fmaf(a1.z, wreg[j][6], p);  p = fmaf(a1.w, wreg[j][7], p);
                p = fmaf(a2v.x, wreg[j][8], p); p = fmaf(a2v.y, wreg[j][9], p);
                p = fmaf(a2v.z, wreg[j][10], p);p = fmaf(a2v.w, wreg[j][11], p);
                p = fmaf(a3.x, wreg[j][12], p); p = fmaf(a3.y, wreg[j][13], p);
                p = fmaf(a3.z, wreg[j][14], p); p = fmaf(a3.w, wreg[j][15], p);
                acc[j] += fmaxf(__bfloat162float(sb0[j]) + p, 0.f);
                float q = breg[j];
                q = fmaf(b0.x, wreg[j][0], q);  q = fmaf(b0.y, wreg[j][1], q);
                q = fmaf(b0.z, wreg[j][2], q);  q = fmaf(b0.w, wreg[j][3], q);
                q = fmaf(b1.x, wreg[j][4], q);  q = fmaf(b1.y, wreg[j][5], q);
                q = fmaf(b1.z, wreg[j][6], q);  q = fmaf(b1.w, wreg[j][7], q);
                q = fmaf(b2v.x, wreg[j][8], q); q = fmaf(b2v.y, wreg[j][9], q);
                q = fmaf(b2v.z, wreg[j][10], q);q = fmaf(b2v.w, wreg[j][11], q);
                q = fmaf(b3.x, wreg[j][12], q); q = fmaf(b3.y, wreg[j][13], q);
                q = fmaf(b3.z, wreg[j][14], q); q = fmaf(b3.w, wreg[j][15], q);
                acc[j] += fmaxf(__bfloat162float(sb1[j]) + q, 0.f);
            }
        }
        if (idx < end) {
            int ei = eid[idx];
            int s = srcv[ei];
            const float4* ef = (const float4*)(ea + (size_t)ei * 16);
            float4 a0 = ef[0], a1 = ef[1], a2v = ef[2], a3 = ef[3];
            unsigned int sv = *(const unsigned int*)((const short*)(h + (size_t)s * 512) + c0);
            const __hip_bfloat16* sb = (const __hip_bfloat16*)&sv;
#pragma unroll
            for (int j = 0; j < 2; j++) {
                float p = breg[j];
                p = fmaf(a0.x, wreg[j][0], p);  p = fmaf(a0.y, wreg[j][1], p);
                p = fmaf(a0.z, wreg[j][2], p);  p = fmaf(a0.w, wreg[j][3], p);
                p = fmaf(a1.x, wreg[j][4], p);  p = fmaf(a1.y, wreg[j][5], p);
                p = fmaf(a1.z, wreg[j][6], p);  p = fmaf(a1.w, wreg[j][7], p);
                p = fmaf(a2v.x, wreg[j][8], p); p = fmaf(a2v.y, wreg[j][9], p);
                p = fmaf(a2v.z, wreg[j][10], p);p = fmaf(a2v.w, wreg[j][11], p);
                p = fmaf(a3.x, wreg[j][12], p); p = fmaf(a3.y, wreg[j][13], p);
                p = fmaf(a3.z, wreg[j][14], p); p = fmaf(a3.w, wreg[j][15], p);
                acc[j] += fmaxf(__bfloat162float(sb[j]) + p, 0.f);
            }
        }
        __hip_bfloat16 o[2];
        o[0] = __float2bfloat16(acc[0]);
        o[1] = __float2bfloat16(acc[1]);
        *(unsigned int*)((short*)(a2 + (size_t)(n - n0) * 512) + c0) = *(const unsigned int*)o;
    }
}

// ---------------- MFMA GEMM: C[M,N] = A[M,K](bf16) @ B^T[N,K](bf16) ----------
// Round-11: 2-phase double-buffered K-loop (BK=32 per buffer) at bounds
// (256,4). Round-1's dbuf regression was a REGISTER-SPILL artifact (bounds
// (256,5) -> WRITE_SIZE 241MB of scratch); at (256,4) the ~120-reg footprint
// fits. prefetch(t+1) issues BEFORE compute(t); one barrier per K-step drains
// the prefetch while MFMA covers the issue latency.
// Retained: T1 XCD swizzle, LDS-bounce epilogue + nt-stores (MODE 0),
// quad-reduced atomics (MODE 2).
// GRID: x = col-tile (fast), y = row-tile.
template <int MODE>
__global__ __launch_bounds__(256, 4) void mfma_gemm(
    const __hip_bfloat16* __restrict__ A, const __hip_bfloat16* __restrict__ Bhi,
    int M, int K, int N, const float* __restrict__ bias, const float* __restrict__ bng,
    const float* __restrict__ bnb, const int* __restrict__ batch,
    float* __restrict__ psum, __hip_bfloat16* __restrict__ Cout) {
    // 33 KB: K-loop uses [0,16384) as As0|As1|Bh0|Bh1 (4096 shorts each);
    // epilogue reuses all 16896 shorts as a [128][132] C-bounce tile.
    __shared__ __align__(16) short buf[16896];

    int nwg = gridDim.x * gridDim.y;
    int wg = blockIdx.x + gridDim.x * blockIdx.y;
    int q = nwg >> 3, r = nwg & 7;
    int xcd = wg & 7, idx = wg >> 3;
    int swz = (xcd < r) ? (xcd * (q + 1) + idx)
                        : (r * (q + 1) + (xcd - r) * q + idx);
    int bx = swz % gridDim.x, by = swz / gridDim.x;

    int r0 = by * 128;
    int n0 = bx * 128;
    int tid = threadIdx.x;
    int lane = tid & 63;
    int wv = tid >> 6;
    int wm = (wv >> 1) * 64, wn = (wv & 1) * 64;

    f32x4 acc[4][4];
#pragma unroll
    for (int i = 0; i < 4; i++)
#pragma unroll
        for (int j = 0; j < 4; j++) acc[i][j] = (f32x4){0.f, 0.f, 0.f, 0.f};

    // staging indices: linear i in [0,512), row = i>>2, kb = i&3; LDS offset = i*16B
    int rowA0 = tid >> 2, cbA0 = tid & 3;
    int rowA1 = (tid + 256) >> 2;  // (tid+256)&3 == tid&3
    int gA0 = r0 + rowA0; if (gA0 >= M) gA0 = M - 1;
    int gA1 = r0 + rowA1; if (gA1 >= M) gA1 = M - 1;
    const __hip_bfloat16* pA0 = A + (size_t)gA0 * K + cbA0 * 8;
    const __hip_bfloat16* pA1 = A + (size_t)gA1 * K + cbA0 * 8;
    const __hip_bfloat16* pB0 = Bhi + (size_t)(n0 + rowA0) * K + cbA0 * 8;
    const __hip_bfloat16* pB1 = Bhi + (size_t)(n0 + rowA1) * K + cbA0 * 8;

    int fi = lane & 15, kb = (lane >> 4) * 8;
    const int NT = K >> 5;
    // prologue: stage tile 0 into buffer 0
    {
        gl2lds16(pA0, buf + wv * 512);
        gl2lds16(pA1, buf + 2048 + wv * 512);
        gl2lds16(pB0, buf + 8192 + wv * 512);
        gl2lds16(pB1, buf + 8192 + 2048 + wv * 512);
    }
#pragma unroll 1
    for (int t = 0; t < NT; t++) {
        __syncthreads();  // drains stage(t) loads; guards buffer reuse
        int cur = (t & 1) * 4096;
        if (t + 1 < NT) {
            int nxt = ((t + 1) & 1) * 4096;
            int kk = (t + 1) << 5;
            gl2lds16(pA0 + kk, buf + nxt + wv * 512);
            gl2lds16(pA1 + kk, buf + nxt + 2048 + wv * 512);
            gl2lds16(pB0 + kk, buf + 8192 + nxt + wv * 512);
            gl2lds16(pB1 + kk, buf + 8192 + nxt + 2048 + wv * 512);
        }
        bf16x8 af[4], bhf[4];
#pragma unroll
        for (int mi = 0; mi < 4; mi++)
            af[mi] = *(const bf16x8*)(buf + cur + (wm + mi * 16 + fi) * 32 + kb);
#pragma unroll
        for (int ni = 0; ni < 4; ni++)
            bhf[ni] = *(const bf16x8*)(buf + 8192 + cur + (wn + ni * 16 + fi) * 32 + kb);
#pragma unroll
        for (int mi = 0; mi < 4; mi++)
#pragma unroll
            for (int ni = 0; ni < 4; ni++)
                acc[mi][ni] = __builtin_amdgcn_mfma_f32_16x16x32_bf16(
                    af[mi], bhf[ni], acc[mi][ni], 0, 0, 0);
    }
    int col_l = lane & 15, quad = lane >> 4;
    if (MODE == 0 || MODE == 1) {
        // ---- LDS-bounce epilogue: fragments -> [128][132] tile -> wide stores
        __syncthreads();  // all K-loop ds_reads complete before overwriting buf
#pragma unroll
        for (int mi = 0; mi < 4; mi++) {
            int rloc = wm + mi * 16 + quad * 4;
#pragma unroll
            for (int ni = 0; ni < 4; ni++) {
                int cloc = wn + ni * 16 + col_l;
                float b0 = bias[n0 + cloc];
                float g0 = 0.f, bb0 = 0.f;
                if (MODE == 1) { g0 = bng[n0 + cloc]; bb0 = bnb[n0 + cloc]; }
#pragma unroll
                for (int reg = 0; reg < 4; reg++) {
                    float v = acc[mi][ni][reg] + b0;
                    if (MODE == 1) v = fmaxf(fmaf(v * bn_inv(), g0, bb0), 0.f);
                    __hip_bfloat16 hv = __float2bfloat16(v);
                    buf[(rloc + reg) * 132 + cloc] = *(const short*)&hv;
                }
            }
        }
        __syncthreads();
        // stream out: 8 rows per pass (32 lanes x 8B = 256B/row, full lines)
#pragma unroll
        for (int p = 0; p < 16; p++) {
            int row = p * 8 + (tid >> 5);
            int grow = r0 + row;
            if (grow < M) {
                int c4 = (tid & 31) * 4;
                unsigned long long v = *(const unsigned long long*)(buf + row * 132 + c4);
                unsigned long long* dst =
                    (unsigned long long*)(Cout + (size_t)grow * N + n0 + c4);
                if (MODE == 0) __builtin_nontemporal_store(v, dst);
                else *dst = v;
            }
        }
    } else {
#pragma unroll
        for (int mi = 0; mi < 4; mi++) {
            int rbase = r0 + wm + mi * 16 + quad * 4;
#pragma unroll
            for (int ni = 0; ni < 4; ni++) {
                int gcol = n0 + wn + ni * 16 + col_l;
                float b0 = bias[gcol], g0 = bng[gcol], bb0 = bnb[gcol];
                float vv[4];
#pragma unroll
                for (int reg = 0; reg < 4; reg++)
                    vv[reg] = fmaxf(fmaf((acc[mi][ni][reg] + b0) * bn_inv(), g0, bb0), 0.f);
                // rows covered by this wave's mi: rtop .. rtop+15 (wave-uniform)
                int rtop = r0 + wm + mi * 16;
                bool uni16 = (rtop + 15 < M) && (batch[rtop] == batch[rtop + 15]);
                float vs = (vv[0] + vv[1]) + (vv[2] + vv[3]);
                if (uni16) {
                    // sum the 4 quads' 4-row partials: lanes ^16, ^32 keep col_l
                    vs += __shfl_xor(vs, 16);
                    vs += __shfl_xor(vs, 32);
                    if (quad == 0)
                        atomicAdd(&psum[(size_t)batch[rtop] * 512 + gcol], vs);
                } else if (rbase + 3 < M && batch[rbase] == batch[rbase + 3]) {
                    atomicAdd(&psum[(size_t)batch[rbase] * 512 + gcol], vs);
                } else {
#pragma unroll
                    for (int reg = 0; reg < 4; reg++) {
                        int grow = rbase + reg;
                        if (grow < M)
                            atomicAdd(&psum[(size_t)batch[grow] * 512 + gcol], vv[reg]);
                    }
                }
            }
        }
    }
}

// ---------------- node counts per graph --------------------------------------
__global__ void count_nodes(const int* __restrict__ batch, float* __restrict__ cnt) {
    int i = blockIdx.x * 256 + threadIdx.x;
    if (i < N_NODESC) atomicAdd(&cnt[batch[i]], 1.0f);
}

// ---------------- finalize pool + assemble xn [B,7,512] bf16 -----------------
__global__ void build_xn(const float* __restrict__ psum, const float* __restrict__ cnt,
                         const float* __restrict__ ecfp, const float* __restrict__ topo,
                         const float* __restrict__ maccs, const float* __restrict__ estate,
                         const float* __restrict__ rdkit2d, const float* __restrict__ phar2d,
                         __hip_bfloat16* __restrict__ xn) {
    int i = blockIdx.x * 256 + threadIdx.x;
    if (i >= BG * 512) return;
    int bidx = i >> 9, c = i & 511;
    float cv = fmaxf(cnt[bidx], 1.0f);
    __hip_bfloat16* o = xn + (size_t)bidx * 7 * 512;
    o[c] = __float2bfloat16(psum[i] / cv);
    o[512 + c] = __float2bfloat16(ecfp[i]);
    o[2 * 512 + c] = __float2bfloat16(topo[i]);
    o[3 * 512 + c] = __float2bfloat16(maccs[i]);
    o[4 * 512 + c] = __float2bfloat16(estate[i]);
    o[5 * 512 + c] = __float2bfloat16(rdkit2d[i]);
    o[6 * 512 + c] = __float2bfloat16(phar2d[i]);
}

// ---------------- GAT attention (fused gl|gr layout: C[B*7][4096]) -----------
// Round-7: vectorized (G13) -- short4 loads in both phases.
__global__ void gat_attn(const __hip_bfloat16* __restrict__ cg,
                         const float* __restrict__ att, const float* __restrict__ bias,
                         const float* __restrict__ bng, const float* __restrict__ bnb,
                         __hip_bfloat16* __restrict__ zout) {
    int b = blockIdx.x;
    int tid = threadIdx.x;
    int wave = tid >> 6, lane = tid & 63;
    __shared__ float logits[13][4];
    __shared__ float alpha[13][4];
    const size_t base = (size_t)b * 7 * 4096;
    for (int p = wave; p < 52; p += 4) {
        int e = p >> 2, hh = p & 3;
        int se = (e < 7) ? 0 : (e - 6);
        int de = (e < 6) ? (e + 1) : ((e == 6) ? 0 : (e - 6));
        const short* glp = (const short*)(cg + base + (size_t)se * 4096 + hh * 512) + lane * 8;
        const short* grp = (const short*)(cg + base + (size_t)de * 4096 + 2048 + hh * 512) + lane * 8;
        short4 gl0 = ((const short4*)glp)[0], gl1 = ((const short4*)glp)[1];
        short4 gr0 = ((const short4*)grp)[0], gr1 = ((const short4*)grp)[1];
        const float4* ap = (const float4*)(att + hh * 512 + lane * 8);
        float4 a0 = ap[0], a1 = ap[1];
        float s = 0.f, v;
        v = b2f(gl0.x) + b2f(gr0.x); v = (v >= 0.f) ? v : 0.2f * v; s = fmaf(v, a0.x, s);
        v = b2f(gl0.y) + b2f(gr0.y); v = (v >= 0.f) ? v : 0.2f * v; s = fmaf(v, a0.y, s);
        v = b2f(gl0.z) + b2f(gr0.z); v = (v >= 0.f) ? v : 0.2f * v; s = fmaf(v, a0.z, s);
        v = b2f(gl0.w) + b2f(gr0.w); v = (v >= 0.f) ? v : 0.2f * v; s = fmaf(v, a0.w, s);
        v = b2f(gl1.x) + b2f(gr1.x); v = (v >= 0.f) ? v : 0.2f * v; s = fmaf(v, a1.x, s);
        v = b2f(gl1.y) + b2f(gr1.y); v = (v >= 0.f) ? v : 0.2f * v; s = fmaf(v, a1.y, s);
        v = b2f(gl1.z) + b2f(gr1.z); v = (v >= 0.f) ? v : 0.2f * v; s = fmaf(v, a1.z, s);
        v = b2f(gl1.w) + b2f(gr1.w); v = (v >= 0.f) ? v : 0.2f * v; s = fmaf(v, a1.w, s);
#pragma unroll
        for (int off = 32; off; off >>= 1) s += __shfl_down(s, off);
        if (lane == 0) logits[e][hh] = s;
    }
    __syncthreads();
    if (tid < 24) {
        int n = 1 + (tid >> 2), hh = tid & 3;
        float la = logits[n - 1][hh], lb = logits[6 + n][hh];
        float m = fmaxf(la, lb);
        float ea = __expf(la - m), eb = __expf(lb - m);
        float inv = 1.f / (ea + eb);
        alpha[n - 1][hh] = ea * inv;
        alpha[6 + n][hh] = eb * inv;
    } else if (tid < 28) {
        alpha[6][tid & 3] = 1.f;
    }
    __syncthreads();
    // Phase 2: 7*128 units of 4 columns each
    for (int u = tid; u < 7 * 128; u += 256) {
        int n = u >> 7, c4 = (u & 127) * 4;
        float v0 = 0.f, v1 = 0.f, v2 = 0.f, v3 = 0.f;
        const short* g0 = (const short*)(cg + base) + c4;
        if (n == 0) {
#pragma unroll
            for (int hh = 0; hh < 4; hh++) {
                short4 t = *(const short4*)(g0 + hh * 512);
                float a = alpha[6][hh];
                v0 = fmaf(a, b2f(t.x), v0); v1 = fmaf(a, b2f(t.y), v1);
                v2 = fmaf(a, b2f(t.z), v2); v3 = fmaf(a, b2f(t.w), v3);
            }
        } else {
            const short* gn = (const short*)(cg + base + (size_t)n * 4096) + c4;
#pragma unroll
            for (int hh = 0; hh < 4; hh++) {
                short4 t = *(const short4*)(g0 + hh * 512);
                float a = alpha[n - 1][hh];
                v0 = fmaf(a, b2f(t.x), v0); v1 = fmaf(a, b2f(t.y), v1);
                v2 = fmaf(a, b2f(t.z), v2); v3 = fmaf(a, b2f(t.w), v3);
                short4 t2 = *(const short4*)(gn + hh * 512);
                float a2 = alpha[6 + n][hh];
                v0 = fmaf(a2, b2f(t2.x), v0); v1 = fmaf(a2, b2f(t2.y), v1);
                v2 = fmaf(a2, b2f(t2.z), v2); v3 = fmaf(a2, b2f(t2.w), v3);
            }
        }
        float4 bi = *(const float4*)(bias + c4);
        float4 gg = *(const float4*)(bng + c4);
        float4 bb = *(const float4*)(bnb + c4);
        v0 = fmaxf(fmaf(fmaf(v0, 0.25f, bi.x) * bn_inv(), gg.x, bb.x), 0.f);
        v1 = fmaxf(fmaf(fmaf(v1, 0.25f, bi.y) * bn_inv(), gg.y, bb.y), 0.f);
        v2 = fmaxf(fmaf(fmaf(v2, 0.25f, bi.z) * bn_inv(), gg.z, bb.z), 0.f);
        v3 = fmaxf(fmaf(fmaf(v3, 0.25f, bi.w) * bn_inv(), gg.w, bb.w), 0.f);
        __hip_bfloat16 o[4];
        o[0] = __float2bfloat16(v0); o[1] = __float2bfloat16(v1);
        o[2] = __float2bfloat16(v2); o[3] = __float2bfloat16(v3);
        *(short4*)((short*)(zout + (size_t)b * 7 * 512) + n * 512 + c4) = *(const short4*)o;
    }
}

// ---------------- final fc ----------------------------------------------------
__global__ void final_fc(const __hip_bfloat16* __restrict__ z, const float* __restrict__ fcW,
                         const float* __restrict__ fcb, float* __restrict__ out) {
    int b = blockIdx.x * 4 + (threadIdx.x >> 6);
    int lane = threadIdx.x & 63;
    if (b >= BG) return;
    const __hip_bfloat16* row = z + (size_t)b * 7 * 512;
    float s = 0.f;
#pragma unroll
    for (int j = 0; j < 8; j++)
        s = fmaf(__bfloat162float(row[lane + j * 64]), fcW[lane + j * 64], s);
#pragma unroll
    for (int off = 32; off; off >>= 1) s += __shfl_down(s, off);
    if (lane == 0) out[b] = s + fcb[0];
}

extern "C" void kernel_launch(void* const* d_in, const int* in_sizes, int n_in,
                              void* d_out, int out_size, void* d_ws, size_t ws_size,
                              hipStream_t stream) {
    const float* x = (const float*)d_in[0];
    const int* eidx = (const int*)d_in[1];
    const float* eattr = (const float*)d_in[2];
    const int* batch = (const int*)d_in[3];
    const float* ecfp = (const float*)d_in[4];
    const float* topo = (const float*)d_in[5];
    const float* maccs = (const float*)d_in[6];
    const float* estate = (const float*)d_in[7];
    const float* rdkit2d = (const float*)d_in[8];
    const float* phar2d = (const float*)d_in[9];
    const float* g1_W = (const float*)d_in[10];
    const float* g1_b = (const float*)d_in[11];
    const float* e1_W = (const float*)d_in[12];
    const float* e1_b = (const float*)d_in[13];
    const float* bn1_g = (const float*)d_in[14];
    const float* bn1_b = (const float*)d_in[15];
    const float* g2_W = (const float*)d_in[16];
    const float* g2_b = (const float*)d_in[17];
    const float* e2_W = (const float*)d_in[18];
    const float* e2_b = (const float*)d_in[19];
    const float* bn2_g = (const float*)d_in[20];
    const float* bn2_b = (const float*)d_in[21];
    const float* gat1_Wl = (const float*)d_in[22];
    const float* gat1_bl = (const float*)d_in[23];
    const float* gat1_Wr = (const float*)d_in[24];
    const float* gat1_br = (const float*)d_in[25];
    const float* gat1_att = (const float*)d_in[26];
    const float* gat1_bias = (const float*)d_in[27];
    const float* bn3_g = (const float*)d_in[28];
    const float* bn3_b = (const float*)d_in[29];
    const float* gat2_Wl = (const float*)d_in[30];
    const float* gat2_bl = (const float*)d_in[31];
    const float* gat2_Wr = (const float*)d_in[32];
    const float* gat2_br = (const float*)d_in[33];
    const float* gat2_att = (const float*)d_in[34];
    const float* gat2_bias = (const float*)d_in[35];
    const float* bn4_g = (const float*)d_in[36];
    const float* bn4_b = (const float*)d_in[37];
    const float* fc_W = (const float*)d_in[38];
    const float* fc_b = (const float*)d_in[39];
    float* out = (float*)d_out;

    const size_t NEEDED = 194682880ull;
    if (ws_size < NEEDED) {
        zero_out<<<(BG + 255) / 256, 256, 0, stream>>>(out, BG);
        return;
    }
    char* w = (char*)d_ws;
    __hip_bfloat16* H = (__hip_bfloat16*)w;
    __hip_bfloat16* CG = (__hip_bfloat16*)w;
    __hip_bfloat16* A2 = (__hip_bfloat16*)(w + 102400000);
    __hip_bfloat16* GW12 = (__hip_bfloat16*)(w + 117440512);
    __hip_bfloat16* GW34 = (__hip_bfloat16*)(w + 121634816);
    __hip_bfloat16* Z1B = (__hip_bfloat16*)(w + 125829120);
    float* B12 = (float*)(w + 140509184);
    float* B34 = (float*)(w + 140525568);

    char* C = w + 161120256;
    __hip_bfloat16* XIN = (__hip_bfloat16*)C;
    __hip_bfloat16* XNB = (__hip_bfloat16*)C;
    __hip_bfloat16* Z2B = (__hip_bfloat16*)(C + 14680064);
    int* ROWPTR = (int*)(C + 14680064);
    int* CURSOR = (int*)(C + 15080192);
    int* EID = (int*)(C + 15480320);
    int* DEG = (int*)(C + 16280320);
    __hip_bfloat16* G1W = (__hip_bfloat16*)(C + 16680320);
    __hip_bfloat16* G2W = (__hip_bfloat16*)(C + 16745856);
    int* BSUM = (int*)(C + 17270144);

    float* PS = (float*)(w + 190480384);
    float* PC = (float*)(w + 194674688);

    const int* src = eidx;
    const int* dst = eidx + N_EDGESC;

    // ---- CSR build ----
    zero_int<<<(N_NODESC + 255) / 256, 256, 0, stream>>>(DEG, N_NODESC);
    zero_f4<<<(BG * 512 / 4 + 255) / 256, 256, 0, stream>>>((float4*)PS, BG * 512 / 4);
    zero_f4<<<(BG / 4 + 255) / 256, 256, 0, stream>>>((float4*)PC, BG / 4);
    hist_dst<<<(N_EDGESC + 255) / 256, 256, 0, stream>>>(dst, DEG);
    const int NB = (N_NODESC + 1023) / 1024;  // 98
    scan_bsums<<<NB, 256, 0, stream>>>(DEG, BSUM, N_NODESC);
    scan_top<<<1, 64, 0, stream>>>(BSUM, NB, ROWPTR + N_NODESC);
    scan_final<<<NB, 256, 0, stream>>>(DEG, BSUM, ROWPTR, CURSOR, N_NODESC);
    scatter_eid<<<(N_EDGESC + 255) / 256, 256, 0, stream>>>(dst, CURSOR, EID);

    // ---- GINE weight prep ----
    transpose_w<<<dim3(1, 8), 256, 0, stream>>>(g1_W, G1W, 64, 512);
    transpose_w<<<dim3(8, 8), 256, 0, stream>>>(g2_W, G2W, 512, 512);

    // ---- GINE1 ----
    gine1_gather<<<(N_NODESC + 4 * G1_NPW - 1) / (4 * G1_NPW), 256, 0, stream>>>(
        x, src, eattr, e1_W, e1_b, ROWPTR, EID, XIN);
    mfma_gemm<1><<<dim3(4, (N_NODESC + 127) / 128), 256, 0, stream>>>(
        XIN, G1W, N_NODESC, 64, 512, g1_b, bn1_g, bn1_b, nullptr, nullptr, H);
    count_nodes<<<(N_NODESC + 255) / 256, 256, 0, stream>>>(batch, PC);

    // ---- GINE2: 2 chunks of 50k nodes ----
    for (int c0n = 0; c0n < N_NODESC; c0n += 50000) {
        int c1n = c0n + 50000;
        int rows = 50000;
        gine2_gather<<<(rows + G2_NPB - 1) / G2_NPB, 256, 0, stream>>>(
            H, src, eattr, e2_W, e2_b, ROWPTR, EID, A2, c0n, c1n);
        mfma_gemm<2><<<dim3(4, (rows + 127) / 128), 256, 0, stream>>>(
            A2, G2W, rows, 512, 512, g2_b, bn2_g, bn2_b, batch + c0n, PS, nullptr);
    }

    // ---- GAT weight prep (H and A2 dead) ----
    transpose_w<<<dim3(8, 32), 256, 0, stream>>>(gat1_Wl, GW12, 512, 2048);
    transpose_w<<<dim3(8, 32), 256, 0, stream>>>(gat1_Wr, GW12 + (size_t)2048 * 512, 512, 2048);
    transpose_w<<<dim3(8, 32), 256, 0, stream>>>(gat2_Wl, GW34, 512, 2048);
    transpose_w<<<dim3(8, 32), 256, 0, stream>>>(gat2_Wr, GW34 + (size_t)2048 * 512, 512, 2048);
    concat_bias<<<8, 256, 0, stream>>>(gat1_bl, gat1_br, B12);
    concat_bias<<<8, 256, 0, stream>>>(gat2_bl, gat2_br, B34);

    // ---- pool -> xn ----
    build_xn<<<(BG * 512) / 256, 256, 0, stream>>>(PS, PC, ecfp, topo, maccs, estate,
                                                   rdkit2d, phar2d, XNB);
    // ---- GAT layer 1 (fused L|R: N = 4096) ----
    const int MGAT = BG * 7;  // 14336
    dim3 ggrid(4096 / 128, MGAT / 128);
    mfma_gemm<0><<<ggrid, 256, 0, stream>>>(XNB, GW12, MGAT, 512, 4096, B12,
                                            nullptr, nullptr, nullptr, nullptr, CG);
    gat_attn<<<BG, 256, 0, stream>>>(CG, gat1_att, gat1_bias, bn3_g, bn3_b, Z1B);
    // ---- GAT layer 2 ----
    mfma_gemm<0><<<ggrid, 256, 0, stream>>>(Z1B, GW34, MGAT, 512, 4096, B34,
                                            nullptr, nullptr, nullptr, nullptr, CG);
    gat_attn<<<BG, 256, 0, stream>>>(CG, gat2_att, gat2_bias, bn4_g, bn4_b, Z2B);
    // ---- final fc ----
    final_fc<<<BG / 4, 256, 0, stream>>>(Z2B, fc_W, fc_b, out);
}